// Round 5
// baseline (12351.769 us; speedup 1.0000x reference)
//
#include <hip/hip_runtime.h>
#include <math.h>

#define BSZ 64
#define PLEN 128
#define HLEN 64
#define EDIM 300
#define HDIM 512
#define G4 2048   // 4*HDIM
#define NCLS 3

// att tag offset: lstm layer-2 reuses rA/rB for its h exchange (tags 129..192);
// att tags start at 1000+ so stale lstm tags can never falsely match.
#define TOFF 1000u
// spin guard: protocol-correct runs never hit it; a bug degrades to a
// wrong answer (reportable) instead of a hung container.
#define SPIN_CAP (1 << 18)

// chunked 512-float vector layout: 4 chunks of 132 floats (128 data + 4 pad).
// float f (0..511) lives at CH(f) = (f>>7)*132 + (f&127).
// GEMV chunk read c*132+4k -> banks 4c+4k: conflict-free broadcast.
#define CHROW 528
#define CH(f) ((((f) >> 7) * 132) + ((f) & 127))

__device__ __forceinline__ float sigf(float x) { return 1.0f / (1.0f + __expf(-x)); }
__device__ __forceinline__ float tanhfast(float x) { return 1.0f - 2.0f / (__expf(2.0f * x) + 1.0f); }

// relaxed agent-scope atomic helpers: LLC-coherent, no L2 flush/invalidate
__device__ __forceinline__ unsigned long long aload64(const unsigned long long* p) {
    return __hip_atomic_load(p, __ATOMIC_RELAXED, __HIP_MEMORY_SCOPE_AGENT);
}
__device__ __forceinline__ void astore64(unsigned long long* p, unsigned long long v) {
    __hip_atomic_store(p, v, __ATOMIC_RELAXED, __HIP_MEMORY_SCOPE_AGENT);
}
// tagged-value pack: high 32 = step tag, low 32 = float bits.
__device__ __forceinline__ unsigned long long tpack(float v, unsigned tag) {
    return ((unsigned long long)tag << 32) | (unsigned long long)__float_as_uint(v);
}
__device__ __forceinline__ float tval(unsigned long long v) { return __uint_as_float((unsigned)v); }
__device__ __forceinline__ unsigned ttag(unsigned long long v) { return (unsigned)(v >> 32); }

__global__ __launch_bounds__(256) void ws_zero(unsigned long long* p) {
    p[(size_t)blockIdx.x * 256 + threadIdx.x] = 0ull;
}

// ---------------------------------------------------------------------------
// persistent LSTM with FUSED input projection. 256 blocks x 256 threads.
// block = (ug 0..31, bg 0..7): units u0..u0+15 (x4 gates), batches b0..b0+7.
// Per step: x-GEMV (Wih in LDS, emb double-buffered) runs BEFORE the h spin
// so HBM/LLC latency and poll time hide under real work. h exchange is
// tagged-data (masked re-poll: only unmatched lanes re-load).
__global__ __launch_bounds__(256, 1) void lstm_coop(
    const int* __restrict__ premise, const int* __restrict__ hyp,
    const float* __restrict__ emb,
    const float* __restrict__ Wih1, const float* __restrict__ bih1,
    const float* __restrict__ bhh1, const float* __restrict__ Whh1,
    const float* __restrict__ Wih2, const float* __restrict__ bih2,
    const float* __restrict__ bhh2, const float* __restrict__ Whh2,
    float* __restrict__ outp, float* __restrict__ outh,
    unsigned long long* __restrict__ hA, unsigned long long* __restrict__ hB,
    unsigned long long* __restrict__ hC, unsigned long long* __restrict__ hD)
{
    const int tid = threadIdx.x;
    const int ug = blockIdx.x & 31;
    const int bg = blockIdx.x >> 5;
    const int u0 = ug * 16, b0 = bg * 8;
    const int r = tid >> 2, c = tid & 3;   // r 0..63 = g*16+uu
    const int g = r >> 4, uur = r & 15;

    // LDS: 77.8K wih + 19.5K ebuf + 16.9K hst + 2.3K gsm + 6K tkl + 0.5K bs
    __shared__ __align__(16) float wih[64 * 304];     // 64 gate-rows x 300 (+4 pad)
    __shared__ __align__(16) float ebuf[2][8 * 304];  // emb rows, double-buffered
    __shared__ __align__(16) float hst[8 * CHROW];    // chunked h staging
    __shared__ float gsm[64][9];
    __shared__ float bs[128];                          // bias sums, layer1|layer2
    __shared__ int tkl[8 * 192];                       // tokens, both sequences

    // ---- prologue staging
    for (int i = tid; i < 8 * 192; i += 256) {
        int bb = i / 192, tt = i % 192;
        tkl[i] = (tt < PLEN) ? premise[(b0 + bb) * PLEN + tt]
                             : hyp[(b0 + bb) * HLEN + (tt - PLEN)];
    }
    for (int i = tid; i < 64 * 76; i += 256) {
        int row = i / 76, f4 = i % 76;
        int grow = (row >> 4) * HDIM + u0 + (row & 15);
        float4 v = (f4 < 75) ? ((const float4*)(Wih1 + (size_t)grow * EDIM))[f4]
                             : make_float4(0.f, 0.f, 0.f, 0.f);
        *((float4*)&wih[row * 304] + f4) = v;
    }
    if (tid < 64) {
        int grow = (tid >> 4) * HDIM + u0 + (tid & 15);
        bs[tid]      = bih1[grow] + bhh1[grow];
        bs[64 + tid] = bih2[grow] + bhh2[grow];
    }
    float4 w[32];
    {
        const float4* src = (const float4*)(Whh1 + ((size_t)(g * HDIM + u0 + uur)) * HDIM) + c * 32;
#pragma unroll
        for (int k = 0; k < 32; k++) w[k] = src[k];
    }
    __syncthreads();
    // ebuf[0] for t=0 (reads tkl)
    for (int i = tid; i < 608; i += 256) {
        int bb = i / 76, f4 = i % 76;
        int tok = tkl[bb * 192];
        float4 v = (f4 < 75) ? ((const float4*)(emb + (size_t)tok * EDIM))[f4]
                             : make_float4(0.f, 0.f, 0.f, 0.f);
        *((float4*)&ebuf[0][bb * 304] + f4) = v;
    }
    __syncthreads();

    float creg = 0.0f;                       // cell state (tid<128); carries c_p
    const int bbc = tid >> 4, uuc = tid & 15;

    for (int t = 0; t < PLEN + HLEN; t++) {
        const int layer2 = (t >= PLEN) ? 1 : 0;
        const int tloc = layer2 ? t - PLEN : t;
        const int T = layer2 ? HLEN : PLEN;
        float* outseq = layer2 ? outh : outp;
        unsigned long long* wA = layer2 ? hC : hA;
        unsigned long long* wB = layer2 ? hD : hB;
        unsigned long long* hwr = (t & 1) ? wB : wA;
        const unsigned long long* hrd = (t & 1) ? wA : wB;

        // A: issue emb prefetch for step t+1 (latency hides under x-GEMV+spin)
        float4 pf0 = make_float4(0.f, 0.f, 0.f, 0.f);
        float4 pf1 = pf0, pf2 = pf0;
        const bool havepf = (t + 1 < PLEN + HLEN);
        const int i2 = tid + 512;
        if (havepf) {
            {   int bb = tid / 76, f4 = tid % 76;
                int tok = tkl[bb * 192 + t + 1];
                if (f4 < 75) pf0 = ((const float4*)(emb + (size_t)tok * EDIM))[f4]; }
            {   int i1 = tid + 256; int bb = i1 / 76, f4 = i1 % 76;
                int tok = tkl[bb * 192 + t + 1];
                if (f4 < 75) pf1 = ((const float4*)(emb + (size_t)tok * EDIM))[f4]; }
            if (i2 < 608) {
                int bb = i2 / 76, f4 = i2 % 76;
                int tok = tkl[bb * 192 + t + 1];
                if (f4 < 75) pf2 = ((const float4*)(emb + (size_t)tok * EDIM))[f4]; }
        }

        // B: layer switch (uniform branch): reload Whh2 regs + Wih2 LDS
        if (t == PLEN) {
            const float4* src = (const float4*)(Whh2 + ((size_t)(g * HDIM + u0 + uur)) * HDIM) + c * 32;
#pragma unroll
            for (int k = 0; k < 32; k++) w[k] = src[k];
            for (int i = tid; i < 64 * 76; i += 256) {
                int row = i / 76, f4 = i % 76;
                int grow = (row >> 4) * HDIM + u0 + (row & 15);
                float4 v = (f4 < 75) ? ((const float4*)(Wih2 + (size_t)grow * EDIM))[f4]
                                     : make_float4(0.f, 0.f, 0.f, 0.f);
                *((float4*)&wih[row * 304] + f4) = v;
            }
            __syncthreads();   // wih2 visible before x-GEMV reads it
        }

        // C: x-GEMV (off the h critical path): thread (r,c) x 19 f4-K x 8 batches
        float xacc[8];
#pragma unroll
        for (int bb = 0; bb < 8; bb++) xacc[bb] = 0.f;
        {
            const float4* wx = (const float4*)&wih[r * 304] + c * 19;
            const float* ebp = &ebuf[t & 1][0];
#pragma unroll
            for (int k = 0; k < 19; k++) {
                float4 wv4 = wx[k];
#pragma unroll
                for (int bb = 0; bb < 8; bb++) {
                    float4 ev = *((const float4*)&ebp[bb * 304] + c * 19 + k);
                    xacc[bb] += wv4.x * ev.x + wv4.y * ev.y + wv4.z * ev.z + wv4.w * ev.w;
                }
            }
        }

        // D: tagged spin for h_{t-1} (masked re-poll: only unmatched lanes reload)
        const bool have_h = (tloc != 0);
        unsigned long long v[16];
        if (have_h) {
            const unsigned long long* src = hrd + (size_t)b0 * 512;
            const unsigned expt = (unsigned)t;
#pragma unroll
            for (int i = 0; i < 16; i++) v[i] = aload64(src + tid + i * 256);
            int guard = 0;
            while (true) {
                bool ok = true;
#pragma unroll
                for (int i = 0; i < 16; i++) ok &= (ttag(v[i]) == expt);
                if (__all(ok)) break;
                if (++guard > SPIN_CAP) break;
                __builtin_amdgcn_s_sleep(1);
#pragma unroll
                for (int i = 0; i < 16; i++)
                    if (ttag(v[i]) != expt) v[i] = aload64(src + tid + i * 256);
            }
            __asm__ volatile("" ::: "memory");
        }

        // E: LDS writes (h staging chunked; prefetched emb rows to alt buffer)
        if (have_h) {
#pragma unroll
            for (int i = 0; i < 16; i++) {
                int idx = tid + i * 256;
                int bb = idx >> 9, u = idx & 511;
                hst[bb * CHROW + CH(u)] = tval(v[i]);
            }
        }
        if (havepf) {
            float* ep = &ebuf[(t + 1) & 1][0];
            *((float4*)&ep[(tid / 76) * 304] + (tid % 76)) = pf0;
            {   int i1 = tid + 256;
                *((float4*)&ep[(i1 / 76) * 304] + (i1 % 76)) = pf1; }
            if (i2 < 608)
                *((float4*)&ep[(i2 / 76) * 304] + (i2 % 76)) = pf2;
        }
        __syncthreads();   // F: hst+ebuf ready; prev-step gsm reads all done

        // G: h-GEMV (weights in VGPRs, h broadcast from LDS) + x merge + reduce
#pragma unroll 1
        for (int bb = 0; bb < 8; bb++) {
            float acc;
            if (have_h) {
                const float4* hv = (const float4*)&hst[bb * CHROW + c * 132];
                float ax = 0.f, ay = 0.f, az = 0.f, aw = 0.f;
#pragma unroll
                for (int k = 0; k < 32; k++) {
                    float4 a = w[k], x = hv[k];
                    ax += a.x * x.x; ay += a.y * x.y; az += a.z * x.z; aw += a.w * x.w;
                }
                acc = (ax + ay) + (az + aw) + xacc[bb];
            } else {
                acc = xacc[bb];
            }
            acc += __shfl_xor(acc, 1);
            acc += __shfl_xor(acc, 2);
            if (c == 0) gsm[r][bb] = acc;
        }
        __syncthreads();   // H: gsm ready

        // I: cell update
        if (tid < 128) {
            const int b = b0 + bbc;
            const float* bsl = &bs[layer2 * 64];
            float gi = gsm[uuc][bbc]      + bsl[uuc];
            float gf = gsm[16 + uuc][bbc] + bsl[16 + uuc];
            float gg = gsm[32 + uuc][bbc] + bsl[32 + uuc];
            float go = gsm[48 + uuc][bbc] + bsl[48 + uuc];
            float cn = sigf(gf) * creg + sigf(gi) * tanhfast(gg);
            float hn = sigf(go) * tanhfast(cn);
            creg = cn;
            astore64(hwr + (size_t)b * 512 + u0 + uuc, tpack(hn, (unsigned)(t + 1)));
            outseq[((size_t)b * T + tloc) * HDIM + u0 + uuc] = hn;
        }
    }
}

// ---------------------------------------------------------------------------
// a1t[b][p][h] = sum_j Wy[h][j] * outp[b][p][j]   (layout [b][p][h])
__global__ __launch_bounds__(256) void a1_kernel(
    const float* __restrict__ Wy, const float* __restrict__ outp,
    float* __restrict__ a1t)
{
    __shared__ float os[32 * 132];
    __shared__ float wsh[64 * 132];
    const int b = blockIdx.x, p0 = blockIdx.y * 32, h0 = blockIdx.z * 64;
    const int tid = threadIdx.x;
    const int tx = tid & 15, ty = tid >> 4;
    float acc[2][4] = {{0.f, 0.f, 0.f, 0.f}, {0.f, 0.f, 0.f, 0.f}};
    for (int kc = 0; kc < 4; kc++) {
        if (kc) __syncthreads();
        for (int i = tid; i < 1024; i += 256) {
            int row = i >> 5, k4 = i & 31;
            ((float4*)os)[row * 33 + k4] =
                ((const float4*)(outp + ((size_t)(b * PLEN) + p0 + row) * HDIM + kc * 128))[k4];
        }
        for (int i = tid; i < 2048; i += 256) {
            int row = i >> 5, k4 = i & 31;
            ((float4*)wsh)[row * 33 + k4] =
                ((const float4*)(Wy + (size_t)(h0 + row) * HDIM + kc * 128))[k4];
        }
        __syncthreads();
        const float4* o0 = (const float4*)os + ty * 33;
        const float4* o1 = o0 + 16 * 33;
        const float4* w0 = (const float4*)wsh + tx * 33;
#pragma unroll
        for (int k = 0; k < 32; k++) {
            float4 ea = o0[k], eb = o1[k];
#pragma unroll
            for (int j = 0; j < 4; j++) {
                float4 w = w0[k + j * 528];
                acc[0][j] += ea.x * w.x + ea.y * w.y + ea.z * w.z + ea.w * w.w;
                acc[1][j] += eb.x * w.x + eb.y * w.y + eb.z * w.z + eb.w * w.w;
            }
        }
    }
#pragma unroll
    for (int j = 0; j < 4; j++) {
        int hh = h0 + tx + j * 16;
        a1t[((size_t)b * PLEN + p0 + ty) * HDIM + hh]      = acc[0][j];
        a1t[((size_t)b * PLEN + p0 + ty + 16) * HDIM + hh] = acc[1][j];
    }
}

// ---------------------------------------------------------------------------
// persistent attention, tagged-data synced (masked re-poll). 256 blocks x 256.
#define OSTR 2056   // 128*16 + 8 pad
__global__ __launch_bounds__(256, 1) void att_coop(
    const float* __restrict__ outh, const float* __restrict__ a1b,
    const float* __restrict__ outp,
    const float* __restrict__ Wh, const float* __restrict__ Wr,
    const float* __restrict__ Wt, const float* __restrict__ wv,
    unsigned long long* __restrict__ a2buf, unsigned long long* __restrict__ sbuf,
    unsigned long long* __restrict__ rA, unsigned long long* __restrict__ rB)
{
    const int tid = threadIdx.x;
    const int ug = blockIdx.x & 31;
    const int bg = blockIdx.x >> 5;
    const int u0 = ug * 16, b0 = bg * 8;
    const int r = tid >> 2, c = tid & 3;   // r<48: m = r>>4 (0:Wh 1:Wr 2:Wt)
    const int m = r >> 4, uur = r & 15;

    __shared__ __align__(16) float ops[8 * OSTR];    // persistent outp slice
    __shared__ __align__(16) float qa[8 * CHROW];    // chunked: q_t (A) / a2 (B)
    __shared__ __align__(16) float rst[8 * CHROW];   // chunked r staging
    __shared__ __align__(16) float scst[8][132];
    __shared__ float dsm[48][9];
    __shared__ float tts[16][9];
    __shared__ __align__(16) float wvs[512];

    float4 w[32];
    if (r < 48) {
        const float* W = (m == 0) ? Wh : ((m == 1) ? Wr : Wt);
        const float4* src = (const float4*)(W + (size_t)(u0 + uur) * HDIM) + c * 32;
#pragma unroll
        for (int k = 0; k < 32; k++) w[k] = src[k];
    }
    for (int i = tid; i < 128; i += 256)
        ((float4*)wvs)[i] = ((const float4*)wv)[i];

    // one-time: outp slice -> LDS
    for (int i = tid; i < 8 * 128 * 4; i += 256) {
        int bb = i >> 9;
        int rem = i & 511;
        int p = rem >> 2, q = rem & 3;
        float4 v = *((const float4*)(outp + ((size_t)(b0 + bb) * PLEN + p) * HDIM + u0) + q);
        *((float4*)(ops + bb * OSTR + p * 16) + q) = v;
    }

    // one-time: a1 slice -> VGPRs
    const int wvid = tid >> 6, lane = tid & 63;
    const int p0g = ug * 4;
    float4 a1r[8][2];
#pragma unroll
    for (int i = 0; i < 8; i++) {
        int pr = wvid * 8 + i;
        int bb = pr >> 2, pp = pr & 3;
        const float4* src = (const float4*)(a1b + ((size_t)(b0 + bb) * PLEN + p0g + pp) * HDIM) + lane;
        a1r[i][0] = src[0];
        a1r[i][1] = src[64];
    }

    const int bbc = tid >> 4, uuc = tid & 15;

    for (int t = 0; t < HLEN; t++) {
        unsigned long long* rwr = (t & 1) ? rB : rA;
        const unsigned long long* rrd = (t & 1) ? rA : rB;

        // ---- phase A: a2 = q.Wh + r.Wr ; tt = tanh(r.Wt)
        for (int i = tid; i < 8 * 128; i += 256) {
            int bb = i >> 7, k4 = i & 127;
            float4 v = ((const float4*)(outh + ((size_t)(b0 + bb) * HLEN + t) * HDIM))[k4];
            *(float4*)&qa[bb * CHROW + CH(4 * k4)] = v;
        }
        if (t > 0) {
            const unsigned long long* src = rrd + (size_t)b0 * 512;
            unsigned long long v[16];
            const unsigned expt = TOFF + (unsigned)(3 * t);
#pragma unroll
            for (int i = 0; i < 16; i++) v[i] = aload64(src + tid + i * 256);
            int guard = 0;
            while (true) {
                bool ok = true;
#pragma unroll
                for (int i = 0; i < 16; i++) ok &= (ttag(v[i]) == expt);
                if (__all(ok)) break;
                if (++guard > SPIN_CAP) break;
                __builtin_amdgcn_s_sleep(1);
#pragma unroll
                for (int i = 0; i < 16; i++)
                    if (ttag(v[i]) != expt) v[i] = aload64(src + tid + i * 256);
            }
            __asm__ volatile("" ::: "memory");
#pragma unroll
            for (int i = 0; i < 16; i++) {
                int idx = tid + i * 256;
                int bb = idx >> 9, u = idx & 511;
                rst[bb * CHROW + CH(u)] = tval(v[i]);
            }
        }
        __syncthreads();
        if (r < 48 && (t > 0 || m == 0)) {
#pragma unroll 1
            for (int bb = 0; bb < 8; bb++) {
                const float4* sv = (const float4*)((m == 0) ? &qa[bb * CHROW + c * 132]
                                                            : &rst[bb * CHROW + c * 132]);
                float ax = 0.f, ay = 0.f, az = 0.f, aw = 0.f;
#pragma unroll
                for (int k = 0; k < 32; k++) {
                    float4 a = w[k], x = sv[k];
                    ax += a.x * x.x; ay += a.y * x.y; az += a.z * x.z; aw += a.w * x.w;
                }
                float acc = (ax + ay) + (az + aw);
                acc += __shfl_xor(acc, 1);
                acc += __shfl_xor(acc, 2);
                if (c == 0) dsm[r][bb] = acc;
            }
        }
        __syncthreads();
        if (tid < 128) {
            float aq = dsm[uuc][bbc];
            float ar = (t > 0) ? dsm[16 + uuc][bbc] : 0.0f;
            float at = (t > 0) ? dsm[32 + uuc][bbc] : 0.0f;
            float a2v = aq + ar;
            tts[uuc][bbc] = (t > 0) ? tanhfast(at) : 0.0f;
            astore64(a2buf + (size_t)(b0 + bbc) * 512 + u0 + uuc,
                     tpack(a2v, TOFF + (unsigned)(3 * t + 1)));
        }

        // ---- phase B: s[b][p-slice] = sum_h wv[h]*tanh(a1 + a2)
        {
            const unsigned long long* src = a2buf + (size_t)b0 * 512;
            unsigned long long v[16];
            const unsigned expt = TOFF + (unsigned)(3 * t + 1);
#pragma unroll
            for (int i = 0; i < 16; i++) v[i] = aload64(src + tid + i * 256);
            int guard = 0;
            while (true) {
                bool ok = true;
#pragma unroll
                for (int i = 0; i < 16; i++) ok &= (ttag(v[i]) == expt);
                if (__all(ok)) break;
                if (++guard > SPIN_CAP) break;
                __builtin_amdgcn_s_sleep(1);
#pragma unroll
                for (int i = 0; i < 16; i++)
                    if (ttag(v[i]) != expt) v[i] = aload64(src + tid + i * 256);
            }
            __asm__ volatile("" ::: "memory");
#pragma unroll
            for (int i = 0; i < 16; i++) {
                int idx = tid + i * 256;
                int bb = idx >> 9, u = idx & 511;
                qa[bb * CHROW + CH(u)] = tval(v[i]);
            }
        }
        __syncthreads();
        {
#pragma unroll 2
            for (int i = 0; i < 8; i++) {
                int pr = wvid * 8 + i;
                int bb = pr >> 2, pp = pr & 3;
                float s = 0.f;
#pragma unroll
                for (int k = 0; k < 2; k++) {
                    int h4 = lane + 64 * k;
                    float4 av = a1r[i][k];
                    float4 a2v = *(const float4*)&qa[bb * CHROW + CH(4 * h4)];
                    float4 wv4 = ((const float4*)wvs)[h4];
                    s += wv4.x * tanhfast(av.x + a2v.x)
                       + wv4.y * tanhfast(av.y + a2v.y)
                       + wv4.z * tanhfast(av.z + a2v.z)
                       + wv4.w * tanhfast(av.w + a2v.w);
                }
#pragma unroll
                for (int o = 1; o < 64; o <<= 1) s += __shfl_xor(s, o);
                if (lane == 0)
                    astore64(sbuf + (size_t)(b0 + bb) * PLEN + p0g + pp,
                             tpack(s, TOFF + (unsigned)(3 * t + 2)));
            }
        }

        // ---- phase C: softmax over p (redundant per block) + r update
        {
            const unsigned long long* src = sbuf + (size_t)b0 * 128;
            unsigned long long v[4];
            const unsigned expt = TOFF + (unsigned)(3 * t + 2);
#pragma unroll
            for (int i = 0; i < 4; i++) v[i] = aload64(src + tid + i * 256);
            int guard = 0;
            while (true) {
                bool ok = true;
#pragma unroll
                for (int i = 0; i < 4; i++) ok &= (ttag(v[i]) == expt);
                if (__all(ok)) break;
                if (++guard > SPIN_CAP) break;
                __builtin_amdgcn_s_sleep(1);
#pragma unroll
                for (int i = 0; i < 4; i++)
                    if (ttag(v[i]) != expt) v[i] = aload64(src + tid + i * 256);
            }
            __asm__ volatile("" ::: "memory");
#pragma unroll
            for (int i = 0; i < 4; i++) {
                int idx = tid + i * 256;
                int bb = idx >> 7, j = idx & 127;
                scst[bb][j] = tval(v[i]);
            }
        }
        __syncthreads();
        {
            const int bb = tid >> 5, j = tid & 31;
            float4 v = *(float4*)&scst[bb][j * 4];
            float mx = fmaxf(fmaxf(v.x, v.y), fmaxf(v.z, v.w));
#pragma unroll
            for (int o = 1; o < 32; o <<= 1) mx = fmaxf(mx, __shfl_xor(mx, o));
            float ex = __expf(v.x - mx), ey = __expf(v.y - mx);
            float ez = __expf(v.z - mx), ew = __expf(v.w - mx);
            float ssum = (ex + ey) + (ez + ew);
#pragma unroll
            for (int o = 1; o < 32; o <<= 1) ssum += __shfl_xor(ssum, o);
            float inv = 1.0f / ssum;
            float4 sc4 = make_float4(ex * inv, ey * inv, ez * inv, ew * inv);
            *(float4*)&scst[bb][j * 4] = sc4;
        }
        __syncthreads();
        if (tid < 128) {
            float acc = tts[uuc][bbc];
            const float* opb = ops + bbc * OSTR + uuc;
#pragma unroll 8
            for (int p = 0; p < PLEN; p++)
                acc += scst[bbc][p] * opb[p * 16];
            astore64(rwr + (size_t)(b0 + bbc) * 512 + u0 + uuc,
                     tpack(acc, TOFF + (unsigned)(3 * t + 3)));
        }
    }
}

// ---------------------------------------------------------------------------
// final: rep = tanh(r.fc1^T + b1 + hn.fc2^T + b2); out = rep.fc3^T + b3
__global__ __launch_bounds__(256) void final_kernel(
    const unsigned long long* __restrict__ r2, const float* __restrict__ outh,
    const float* __restrict__ fc1w, const float* __restrict__ fc1b,
    const float* __restrict__ fc2w, const float* __restrict__ fc2b,
    const float* __restrict__ fc3w, const float* __restrict__ fc3b,
    float* __restrict__ out)
{
    int b = blockIdx.x, tid = threadIdx.x;
    __shared__ float rs[HDIM], hs[HDIM], rep[HDIM], red[256];
    for (int i = tid; i < 512; i += 256)
        rs[i] = tval(r2[(size_t)b * 512 + i]);
    for (int i = tid; i < 128; i += 256)
        ((float4*)hs)[i] = ((const float4*)(outh + ((size_t)(b * HLEN + HLEN - 1)) * HDIM))[i];
    __syncthreads();
    for (int u = tid; u < HDIM; u += 256) {
        const float4* w1 = (const float4*)(fc1w + (size_t)u * HDIM);
        const float4* w2 = (const float4*)(fc2w + (size_t)u * HDIM);
        float a = 0.f, bacc = 0.f;
        for (int k = 0; k < 128; k++) {
            float4 rv = ((float4*)rs)[k], hv = ((float4*)hs)[k];
            float4 x = w1[k]; a    += rv.x * x.x + rv.y * x.y + rv.z * x.z + rv.w * x.w;
            float4 y = w2[k]; bacc += hv.x * y.x + hv.y * y.y + hv.z * y.z + hv.w * y.w;
        }
        rep[u] = tanhfast(a + fc1b[u] + bacc + fc2b[u]);
    }
    __syncthreads();
    for (int cix = 0; cix < NCLS; cix++) {
        red[tid] = rep[tid] * fc3w[(size_t)cix * HDIM + tid]
                 + rep[tid + 256] * fc3w[(size_t)cix * HDIM + tid + 256];
        __syncthreads();
        for (int off = 128; off; off >>= 1) {
            if (tid < off) red[tid] += red[tid + off];
            __syncthreads();
        }
        if (tid == 0) out[b * NCLS + cix] = red[0] + fc3b[cix];
        __syncthreads();
    }
}

// ---------------------------------------------------------------------------
extern "C" void kernel_launch(void* const* d_in, const int* in_sizes, int n_in,
                              void* d_out, int out_size, void* d_ws, size_t ws_size,
                              hipStream_t stream)
{
    const int*   premise = (const int*)d_in[0];
    const int*   hyp     = (const int*)d_in[1];
    const float* emb     = (const float*)d_in[2];
    const float* Wih1    = (const float*)d_in[3];
    const float* Whh1    = (const float*)d_in[4];
    const float* bih1    = (const float*)d_in[5];
    const float* bhh1    = (const float*)d_in[6];
    const float* Wih2    = (const float*)d_in[7];
    const float* Whh2    = (const float*)d_in[8];
    const float* bih2    = (const float*)d_in[9];
    const float* bhh2    = (const float*)d_in[10];
    const float* Wy      = (const float*)d_in[11];
    const float* Wh      = (const float*)d_in[12];
    const float* Wr      = (const float*)d_in[13];
    const float* Wt      = (const float*)d_in[14];
    const float* wv      = (const float*)d_in[15];
    const float* fc1w    = (const float*)d_in[16];
    const float* fc1b    = (const float*)d_in[17];
    const float* fc2w    = (const float*)d_in[18];
    const float* fc2b    = (const float*)d_in[19];
    const float* fc3w    = (const float*)d_in[20];
    const float* fc3b    = (const float*)d_in[21];
    float* out = (float*)d_out;

    float* ws = (float*)d_ws;
    size_t off = 0;
    float* outp  = ws + off; off += (size_t)BSZ * PLEN * HDIM;
    float* outhp = ws + off; off += (size_t)BSZ * HLEN * HDIM;
    float* a1b   = ws + off; off += (size_t)BSZ * HDIM * PLEN;   // [b][p][h]
    // tagged u64 exchange buffers (contiguous so one zero-kernel covers all).
    // lstm layer-2 h exchange reuses rA/rB (att tags are TOFF-offset).
    unsigned long long* tbase = (unsigned long long*)(ws + off);
    unsigned long long* hAb   = tbase;
    unsigned long long* hBb   = tbase + 32768;            // 64*512
    unsigned long long* a2buf = tbase + 2 * 32768;
    unsigned long long* rAb   = tbase + 3 * 32768;        // also lstm hC
    unsigned long long* rBb   = tbase + 4 * 32768;        // also lstm hD
    unsigned long long* sbuf  = tbase + 5 * 32768;        // 64*128
    off += (size_t)(5 * 32768 + 8192) * 2;                // in floats
    if (ws_size < off * sizeof(float)) return;

    // zero tagged buffers (172032 u64 = 672 * 256)
    ws_zero<<<dim3(672), dim3(256), 0, stream>>>(tbase);

    // both LSTMs with fused input projection, persistent, tagged-data sync
    lstm_coop<<<dim3(256), dim3(256), 0, stream>>>(
        premise, hyp, emb,
        Wih1, bih1, bhh1, Whh1,
        Wih2, bih2, bhh2, Whh2,
        outp, outhp, hAb, hBb, rAb, rBb);

    // a1t = einsum('hj,bpj->bph', Wy, outp)
    a1_kernel<<<dim3(BSZ, PLEN / 32, HDIM / 64), dim3(256), 0, stream>>>(Wy, outp, a1b);

    // attention recurrence, persistent, tagged-data sync
    att_coop<<<dim3(256), dim3(256), 0, stream>>>(
        outhp, a1b, outp, Wh, Wr, Wt, wv, a2buf, sbuf, rAb, rBb);

    // final classifier: r after step 63 lives in rB (63 & 1 == 1)
    final_kernel<<<dim3(BSZ), dim3(256), 0, stream>>>(
        rBb, outhp, fc1w, fc1b, fc2w, fc2b, fc3w, fc3b, out);
}

// Round 6
// 3771.477 us; speedup vs baseline: 3.2750x; 3.2750x over previous
//
#include <hip/hip_runtime.h>
#include <math.h>

#define BSZ 64
#define PLEN 128
#define HLEN 64
#define EDIM 300
#define HDIM 512
#define G4 2048   // 4*HDIM
#define NCLS 3

// att tag offset: lstm layer-2 reuses rA/rB for its h exchange (tags 129..192);
// att tags start at 1000+ so stale lstm tags can never falsely match.
#define TOFF 1000u
// spin guard: protocol-correct runs never hit it; a bug degrades to a
// wrong answer (reportable) instead of a hung container.
#define SPIN_CAP (1 << 18)

// chunked 512-float vector layout: 4 chunks of 132 floats (128 data + 4 pad).
// float f (0..511) lives at CH(f) = (f>>7)*132 + (f&127).
// GEMV chunk read c*132+4k -> banks 4c+4k: conflict-free broadcast.
#define CHROW 528
#define CH(f) ((((f) >> 7) * 132) + ((f) & 127))

__device__ __forceinline__ float sigf(float x) { return 1.0f / (1.0f + __expf(-x)); }
__device__ __forceinline__ float tanhfast(float x) { return 1.0f - 2.0f / (__expf(2.0f * x) + 1.0f); }

// relaxed agent-scope atomic helpers: LLC-coherent, no L2 flush/invalidate
__device__ __forceinline__ unsigned long long aload64(const unsigned long long* p) {
    return __hip_atomic_load(p, __ATOMIC_RELAXED, __HIP_MEMORY_SCOPE_AGENT);
}
__device__ __forceinline__ void astore64(unsigned long long* p, unsigned long long v) {
    __hip_atomic_store(p, v, __ATOMIC_RELAXED, __HIP_MEMORY_SCOPE_AGENT);
}
// tagged-value pack: high 32 = step tag, low 32 = float bits.
__device__ __forceinline__ unsigned long long tpack(float v, unsigned tag) {
    return ((unsigned long long)tag << 32) | (unsigned long long)__float_as_uint(v);
}
__device__ __forceinline__ float tval(unsigned long long v) { return __uint_as_float((unsigned)v); }
__device__ __forceinline__ unsigned ttag(unsigned long long v) { return (unsigned)(v >> 32); }

__global__ __launch_bounds__(256) void ws_zero(unsigned long long* p) {
    p[(size_t)blockIdx.x * 256 + threadIdx.x] = 0ull;
}

// ---------------------------------------------------------------------------
// input projection GEMM: out[m][row] = emb[toks[m]] . Wih[row] + bih[row]+bhh[row]
// 32x64 tile, 8 outputs/thread (2m x 4n), K chunked by 100.
__global__ __launch_bounds__(256) void proj_kernel(
    const int* __restrict__ toks, const float* __restrict__ emb,
    const float* __restrict__ Wih, const float* __restrict__ bih,
    const float* __restrict__ bhh, float* __restrict__ out)
{
    __shared__ float es[32 * 100];
    __shared__ float wsh[64 * 100];
    __shared__ int tks[32];
    const int m0 = blockIdx.x * 32, r0 = blockIdx.y * 64;
    const int tid = threadIdx.x;
    const int tx = tid & 15, ty = tid >> 4;
    float acc[2][4] = {{0.f, 0.f, 0.f, 0.f}, {0.f, 0.f, 0.f, 0.f}};
    if (tid < 32) tks[tid] = toks[m0 + tid];
    __syncthreads();
    for (int kc = 0; kc < 3; kc++) {
        if (kc) __syncthreads();
        for (int i = tid; i < 800; i += 256) {
            int row = i / 25, k4 = i % 25;
            ((float4*)es)[i] = ((const float4*)(emb + (size_t)tks[row] * EDIM + kc * 100))[k4];
        }
        for (int i = tid; i < 1600; i += 256) {
            int row = i / 25, k4 = i % 25;
            ((float4*)wsh)[i] = ((const float4*)(Wih + (size_t)(r0 + row) * EDIM + kc * 100))[k4];
        }
        __syncthreads();
        const float4* e0 = (const float4*)es + ty * 25;
        const float4* e1 = e0 + 16 * 25;
        const float4* w0 = (const float4*)wsh + tx * 25;
#pragma unroll
        for (int k = 0; k < 25; k++) {
            float4 ea = e0[k], eb = e1[k];
#pragma unroll
            for (int j = 0; j < 4; j++) {
                float4 w = w0[k + j * 400];
                acc[0][j] += ea.x * w.x + ea.y * w.y + ea.z * w.z + ea.w * w.w;
                acc[1][j] += eb.x * w.x + eb.y * w.y + eb.z * w.z + eb.w * w.w;
            }
        }
    }
#pragma unroll
    for (int j = 0; j < 4; j++) {
        int rr = r0 + tx + j * 16;
        float bsum = bih[rr] + bhh[rr];
        out[(size_t)(m0 + ty) * G4 + rr]      = acc[0][j] + bsum;
        out[(size_t)(m0 + ty + 16) * G4 + rr] = acc[1][j] + bsum;
    }
}

// ---------------------------------------------------------------------------
// persistent LSTM, tagged-data synced within batch-groups. 256 blocks x 256 thr.
// XCD-LOCAL MAPPING: bg = blockIdx&7, ug = blockIdx>>3. Under round-robin
// workgroup->XCD dispatch, all 32 blocks of one b-group (the only exchange
// partners) land on the SAME XCD -> exchange locality. Perf-only heuristic.
// h exchange: u64 (tag | h_bits) per (b,u); consumer masked re-poll (only
// unmatched lanes re-load -> ~20x less poll traffic than full re-read).
// Layer 2 uses its own buffer pair (hC/hD) -- layer-boundary WAR fix (R4).
__global__ __launch_bounds__(256, 1) void lstm_coop(
    const float* __restrict__ xp, const float* __restrict__ xh,
    const float* __restrict__ Whh1, const float* __restrict__ Whh2,
    float* __restrict__ outp, float* __restrict__ outh,
    unsigned long long* __restrict__ hA, unsigned long long* __restrict__ hB,
    unsigned long long* __restrict__ hC, unsigned long long* __restrict__ hD)
{
    const int tid = threadIdx.x;
    const int ug = blockIdx.x >> 3;
    const int bg = blockIdx.x & 7;
    const int u0 = ug * 16, b0 = bg * 8;
    const int r = tid >> 2, c = tid & 3;   // r 0..63 = g*16+uu
    const int g = r >> 4, uur = r & 15;

    __shared__ __align__(16) float hst[8 * CHROW];   // chunked h staging
    __shared__ float gsm[64][9];

    float4 w[32];
    {
        const float4* src = (const float4*)(Whh1 + ((size_t)(g * HDIM + u0 + uur)) * HDIM) + c * 32;
#pragma unroll
        for (int k = 0; k < 32; k++) w[k] = src[k];
    }
    float creg = 0.0f;                       // cell state, thread-private (tid<128)
    const int bbc = tid >> 4, uuc = tid & 15;

    for (int t = 0; t < PLEN + HLEN; t++) {
        const int layer2 = (t >= PLEN) ? 1 : 0;
        const int tloc = layer2 ? t - PLEN : t;
        const int T = layer2 ? HLEN : PLEN;
        const float* xproj = layer2 ? xh : xp;
        float* outseq = layer2 ? outh : outp;
        unsigned long long* wA = layer2 ? hC : hA;
        unsigned long long* wB = layer2 ? hD : hB;
        unsigned long long* hwr = (t & 1) ? wB : wA;
        const unsigned long long* hrd = (t & 1) ? wA : wB;

        // prefetch gate pre-activations for THIS step (latency hides under
        // the tag-spin + staging + GEMV)
        float gi = 0.f, gf = 0.f, gg = 0.f, go = 0.f;
        if (tid < 128) {
            size_t xb = ((size_t)(b0 + bbc) * T + tloc) * G4 + u0 + uuc;
            gi = xproj[xb];        gf = xproj[xb + 512];
            gg = xproj[xb + 1024]; go = xproj[xb + 1536];
        }

        if (t == PLEN) {   // reload layer-2 weights into VGPRs (uniform)
            const float4* src = (const float4*)(Whh2 + ((size_t)(g * HDIM + u0 + uur)) * HDIM) + c * 32;
#pragma unroll
            for (int k = 0; k < 32; k++) w[k] = src[k];
        }
        const bool have_h = (tloc != 0);
        if (have_h) {
            // tagged staging, masked re-poll
            const unsigned long long* src = hrd + (size_t)b0 * 512;
            unsigned long long v[16];
            const unsigned expt = (unsigned)t;
#pragma unroll
            for (int i = 0; i < 16; i++) v[i] = aload64(src + tid + i * 256);
            int guard = 0;
            while (true) {
                bool ok = true;
#pragma unroll
                for (int i = 0; i < 16; i++) ok &= (ttag(v[i]) == expt);
                if (__all(ok)) break;
                if (++guard > SPIN_CAP) break;
                __builtin_amdgcn_s_sleep(1);
#pragma unroll
                for (int i = 0; i < 16; i++)
                    if (ttag(v[i]) != expt) v[i] = aload64(src + tid + i * 256);
            }
            __asm__ volatile("" ::: "memory");
#pragma unroll
            for (int i = 0; i < 16; i++) {
                int idx = tid + i * 256;
                int bb = idx >> 9, u = idx & 511;
                hst[bb * CHROW + CH(u)] = tval(v[i]);
            }
            __syncthreads();
            // GEMV: gate row r, chunk c (weights in VGPRs, h broadcast from LDS)
#pragma unroll 1
            for (int bb = 0; bb < 8; bb++) {
                const float4* hv = (const float4*)&hst[bb * CHROW + c * 132];
                float ax = 0.f, ay = 0.f, az = 0.f, aw = 0.f;
#pragma unroll
                for (int k = 0; k < 32; k++) {
                    float4 a = w[k], x = hv[k];
                    ax += a.x * x.x; ay += a.y * x.y; az += a.z * x.z; aw += a.w * x.w;
                }
                float acc = (ax + ay) + (az + aw);
                acc += __shfl_xor(acc, 1);
                acc += __shfl_xor(acc, 2);
                if (c == 0) gsm[r][bb] = acc;
            }
        }
        __syncthreads();   // gsm ready; also protects hst vs next staging
        // cell update: thread (bb, uu), tid<128
        if (tid < 128) {
            const int b = b0 + bbc;
            if (have_h) {
                gi += gsm[uuc][bbc];
                gf += gsm[16 + uuc][bbc];
                gg += gsm[32 + uuc][bbc];
                go += gsm[48 + uuc][bbc];
            }
            float cn = sigf(gf) * creg + sigf(gi) * tanhfast(gg);
            float hn = sigf(go) * tanhfast(cn);
            creg = cn;
            astore64(hwr + (size_t)b * 512 + u0 + uuc, tpack(hn, (unsigned)(t + 1)));
            outseq[((size_t)b * T + tloc) * HDIM + u0 + uuc] = hn;
        }
    }
}

// ---------------------------------------------------------------------------
// a1t[b][p][h] = sum_j Wy[h][j] * outp[b][p][j]   (layout [b][p][h])
__global__ __launch_bounds__(256) void a1_kernel(
    const float* __restrict__ Wy, const float* __restrict__ outp,
    float* __restrict__ a1t)
{
    __shared__ float os[32 * 132];
    __shared__ float wsh[64 * 132];
    const int b = blockIdx.x, p0 = blockIdx.y * 32, h0 = blockIdx.z * 64;
    const int tid = threadIdx.x;
    const int tx = tid & 15, ty = tid >> 4;
    float acc[2][4] = {{0.f, 0.f, 0.f, 0.f}, {0.f, 0.f, 0.f, 0.f}};
    for (int kc = 0; kc < 4; kc++) {
        if (kc) __syncthreads();
        for (int i = tid; i < 1024; i += 256) {
            int row = i >> 5, k4 = i & 31;
            ((float4*)os)[row * 33 + k4] =
                ((const float4*)(outp + ((size_t)(b * PLEN) + p0 + row) * HDIM + kc * 128))[k4];
        }
        for (int i = tid; i < 2048; i += 256) {
            int row = i >> 5, k4 = i & 31;
            ((float4*)wsh)[row * 33 + k4] =
                ((const float4*)(Wy + (size_t)(h0 + row) * HDIM + kc * 128))[k4];
        }
        __syncthreads();
        const float4* o0 = (const float4*)os + ty * 33;
        const float4* o1 = o0 + 16 * 33;
        const float4* w0 = (const float4*)wsh + tx * 33;
#pragma unroll
        for (int k = 0; k < 32; k++) {
            float4 ea = o0[k], eb = o1[k];
#pragma unroll
            for (int j = 0; j < 4; j++) {
                float4 w = w0[k + j * 528];
                acc[0][j] += ea.x * w.x + ea.y * w.y + ea.z * w.z + ea.w * w.w;
                acc[1][j] += eb.x * w.x + eb.y * w.y + eb.z * w.z + eb.w * w.w;
            }
        }
    }
#pragma unroll
    for (int j = 0; j < 4; j++) {
        int hh = h0 + tx + j * 16;
        a1t[((size_t)b * PLEN + p0 + ty) * HDIM + hh]      = acc[0][j];
        a1t[((size_t)b * PLEN + p0 + ty + 16) * HDIM + hh] = acc[1][j];
    }
}

// ---------------------------------------------------------------------------
// persistent attention, tagged-data synced (masked re-poll). 256 blocks x 256.
// XCD-local mapping: bg = blockIdx&7, ug = blockIdx>>3 (same as lstm).
#define OSTR 2056   // 128*16 + 8 pad
__global__ __launch_bounds__(256, 1) void att_coop(
    const float* __restrict__ outh, const float* __restrict__ a1b,
    const float* __restrict__ outp,
    const float* __restrict__ Wh, const float* __restrict__ Wr,
    const float* __restrict__ Wt, const float* __restrict__ wv,
    unsigned long long* __restrict__ a2buf, unsigned long long* __restrict__ sbuf,
    unsigned long long* __restrict__ rA, unsigned long long* __restrict__ rB)
{
    const int tid = threadIdx.x;
    const int ug = blockIdx.x >> 3;
    const int bg = blockIdx.x & 7;
    const int u0 = ug * 16, b0 = bg * 8;
    const int r = tid >> 2, c = tid & 3;   // r<48: m = r>>4 (0:Wh 1:Wr 2:Wt)
    const int m = r >> 4, uur = r & 15;

    __shared__ __align__(16) float ops[8 * OSTR];    // persistent outp slice
    __shared__ __align__(16) float qa[8 * CHROW];    // chunked: q_t (A) / a2 (B)
    __shared__ __align__(16) float rst[8 * CHROW];   // chunked r staging
    __shared__ __align__(16) float scst[8][132];
    __shared__ float dsm[48][9];
    __shared__ float tts[16][9];
    __shared__ __align__(16) float wvs[512];

    float4 w[32];
    if (r < 48) {
        const float* W = (m == 0) ? Wh : ((m == 1) ? Wr : Wt);
        const float4* src = (const float4*)(W + (size_t)(u0 + uur) * HDIM) + c * 32;
#pragma unroll
        for (int k = 0; k < 32; k++) w[k] = src[k];
    }
    for (int i = tid; i < 128; i += 256)
        ((float4*)wvs)[i] = ((const float4*)wv)[i];

    // one-time: outp slice -> LDS
    for (int i = tid; i < 8 * 128 * 4; i += 256) {
        int bb = i >> 9;
        int rem = i & 511;
        int p = rem >> 2, q = rem & 3;
        float4 v = *((const float4*)(outp + ((size_t)(b0 + bb) * PLEN + p) * HDIM + u0) + q);
        *((float4*)(ops + bb * OSTR + p * 16) + q) = v;
    }

    // one-time: a1 slice -> VGPRs
    const int wvid = tid >> 6, lane = tid & 63;
    const int p0g = ug * 4;
    float4 a1r[8][2];
#pragma unroll
    for (int i = 0; i < 8; i++) {
        int pr = wvid * 8 + i;
        int bb = pr >> 2, pp = pr & 3;
        const float4* src = (const float4*)(a1b + ((size_t)(b0 + bb) * PLEN + p0g + pp) * HDIM) + lane;
        a1r[i][0] = src[0];
        a1r[i][1] = src[64];
    }

    const int bbc = tid >> 4, uuc = tid & 15;

    for (int t = 0; t < HLEN; t++) {
        unsigned long long* rwr = (t & 1) ? rB : rA;
        const unsigned long long* rrd = (t & 1) ? rA : rB;

        // ---- phase A: a2 = q.Wh + r.Wr ; tt = tanh(r.Wt)
        for (int i = tid; i < 8 * 128; i += 256) {
            int bb = i >> 7, k4 = i & 127;
            float4 v = ((const float4*)(outh + ((size_t)(b0 + bb) * HLEN + t) * HDIM))[k4];
            *(float4*)&qa[bb * CHROW + CH(4 * k4)] = v;
        }
        if (t > 0) {
            const unsigned long long* src = rrd + (size_t)b0 * 512;
            unsigned long long v[16];
            const unsigned expt = TOFF + (unsigned)(3 * t);
#pragma unroll
            for (int i = 0; i < 16; i++) v[i] = aload64(src + tid + i * 256);
            int guard = 0;
            while (true) {
                bool ok = true;
#pragma unroll
                for (int i = 0; i < 16; i++) ok &= (ttag(v[i]) == expt);
                if (__all(ok)) break;
                if (++guard > SPIN_CAP) break;
                __builtin_amdgcn_s_sleep(1);
#pragma unroll
                for (int i = 0; i < 16; i++)
                    if (ttag(v[i]) != expt) v[i] = aload64(src + tid + i * 256);
            }
            __asm__ volatile("" ::: "memory");
#pragma unroll
            for (int i = 0; i < 16; i++) {
                int idx = tid + i * 256;
                int bb = idx >> 9, u = idx & 511;
                rst[bb * CHROW + CH(u)] = tval(v[i]);
            }
        }
        __syncthreads();
        if (r < 48 && (t > 0 || m == 0)) {
#pragma unroll 1
            for (int bb = 0; bb < 8; bb++) {
                const float4* sv = (const float4*)((m == 0) ? &qa[bb * CHROW + c * 132]
                                                            : &rst[bb * CHROW + c * 132]);
                float ax = 0.f, ay = 0.f, az = 0.f, aw = 0.f;
#pragma unroll
                for (int k = 0; k < 32; k++) {
                    float4 a = w[k], x = sv[k];
                    ax += a.x * x.x; ay += a.y * x.y; az += a.z * x.z; aw += a.w * x.w;
                }
                float acc = (ax + ay) + (az + aw);
                acc += __shfl_xor(acc, 1);
                acc += __shfl_xor(acc, 2);
                if (c == 0) dsm[r][bb] = acc;
            }
        }
        __syncthreads();
        if (tid < 128) {
            float aq = dsm[uuc][bbc];
            float ar = (t > 0) ? dsm[16 + uuc][bbc] : 0.0f;
            float at = (t > 0) ? dsm[32 + uuc][bbc] : 0.0f;
            float a2v = aq + ar;
            tts[uuc][bbc] = (t > 0) ? tanhfast(at) : 0.0f;
            astore64(a2buf + (size_t)(b0 + bbc) * 512 + u0 + uuc,
                     tpack(a2v, TOFF + (unsigned)(3 * t + 1)));
        }

        // ---- phase B: s[b][p-slice] = sum_h wv[h]*tanh(a1 + a2)
        {
            const unsigned long long* src = a2buf + (size_t)b0 * 512;
            unsigned long long v[16];
            const unsigned expt = TOFF + (unsigned)(3 * t + 1);
#pragma unroll
            for (int i = 0; i < 16; i++) v[i] = aload64(src + tid + i * 256);
            int guard = 0;
            while (true) {
                bool ok = true;
#pragma unroll
                for (int i = 0; i < 16; i++) ok &= (ttag(v[i]) == expt);
                if (__all(ok)) break;
                if (++guard > SPIN_CAP) break;
                __builtin_amdgcn_s_sleep(1);
#pragma unroll
                for (int i = 0; i < 16; i++)
                    if (ttag(v[i]) != expt) v[i] = aload64(src + tid + i * 256);
            }
            __asm__ volatile("" ::: "memory");
#pragma unroll
            for (int i = 0; i < 16; i++) {
                int idx = tid + i * 256;
                int bb = idx >> 9, u = idx & 511;
                qa[bb * CHROW + CH(u)] = tval(v[i]);
            }
        }
        __syncthreads();
        {
#pragma unroll 2
            for (int i = 0; i < 8; i++) {
                int pr = wvid * 8 + i;
                int bb = pr >> 2, pp = pr & 3;
                float s = 0.f;
#pragma unroll
                for (int k = 0; k < 2; k++) {
                    int h4 = lane + 64 * k;
                    float4 av = a1r[i][k];
                    float4 a2v = *(const float4*)&qa[bb * CHROW + CH(4 * h4)];
                    float4 wv4 = ((const float4*)wvs)[h4];
                    s += wv4.x * tanhfast(av.x + a2v.x)
                       + wv4.y * tanhfast(av.y + a2v.y)
                       + wv4.z * tanhfast(av.z + a2v.z)
                       + wv4.w * tanhfast(av.w + a2v.w);
                }
#pragma unroll
                for (int o = 1; o < 64; o <<= 1) s += __shfl_xor(s, o);
                if (lane == 0)
                    astore64(sbuf + (size_t)(b0 + bb) * PLEN + p0g + pp,
                             tpack(s, TOFF + (unsigned)(3 * t + 2)));
            }
        }

        // ---- phase C: softmax over p (redundant per block) + r update
        {
            const unsigned long long* src = sbuf + (size_t)b0 * 128;
            unsigned long long v[4];
            const unsigned expt = TOFF + (unsigned)(3 * t + 2);
#pragma unroll
            for (int i = 0; i < 4; i++) v[i] = aload64(src + tid + i * 256);
            int guard = 0;
            while (true) {
                bool ok = true;
#pragma unroll
                for (int i = 0; i < 4; i++) ok &= (ttag(v[i]) == expt);
                if (__all(ok)) break;
                if (++guard > SPIN_CAP) break;
                __builtin_amdgcn_s_sleep(1);
#pragma unroll
                for (int i = 0; i < 4; i++)
                    if (ttag(v[i]) != expt) v[i] = aload64(src + tid + i * 256);
            }
            __asm__ volatile("" ::: "memory");
#pragma unroll
            for (int i = 0; i < 4; i++) {
                int idx = tid + i * 256;
                int bb = idx >> 7, j = idx & 127;
                scst[bb][j] = tval(v[i]);
            }
        }
        __syncthreads();
        {
            const int bb = tid >> 5, j = tid & 31;
            float4 v = *(float4*)&scst[bb][j * 4];
            float mx = fmaxf(fmaxf(v.x, v.y), fmaxf(v.z, v.w));
#pragma unroll
            for (int o = 1; o < 32; o <<= 1) mx = fmaxf(mx, __shfl_xor(mx, o));
            float ex = __expf(v.x - mx), ey = __expf(v.y - mx);
            float ez = __expf(v.z - mx), ew = __expf(v.w - mx);
            float ssum = (ex + ey) + (ez + ew);
#pragma unroll
            for (int o = 1; o < 32; o <<= 1) ssum += __shfl_xor(ssum, o);
            float inv = 1.0f / ssum;
            float4 sc4 = make_float4(ex * inv, ey * inv, ez * inv, ew * inv);
            *(float4*)&scst[bb][j * 4] = sc4;
        }
        __syncthreads();
        if (tid < 128) {
            float acc = tts[uuc][bbc];
            const float* opb = ops + bbc * OSTR + uuc;
#pragma unroll 8
            for (int p = 0; p < PLEN; p++)
                acc += scst[bbc][p] * opb[p * 16];
            astore64(rwr + (size_t)(b0 + bbc) * 512 + u0 + uuc,
                     tpack(acc, TOFF + (unsigned)(3 * t + 3)));
        }
    }
}

// ---------------------------------------------------------------------------
// final: rep = tanh(r.fc1^T + b1 + hn.fc2^T + b2); out = rep.fc3^T + b3
__global__ __launch_bounds__(256) void final_kernel(
    const unsigned long long* __restrict__ r2, const float* __restrict__ outh,
    const float* __restrict__ fc1w, const float* __restrict__ fc1b,
    const float* __restrict__ fc2w, const float* __restrict__ fc2b,
    const float* __restrict__ fc3w, const float* __restrict__ fc3b,
    float* __restrict__ out)
{
    int b = blockIdx.x, tid = threadIdx.x;
    __shared__ float rs[HDIM], hs[HDIM], rep[HDIM], red[256];
    for (int i = tid; i < 512; i += 256)
        rs[i] = tval(r2[(size_t)b * 512 + i]);
    for (int i = tid; i < 128; i += 256)
        ((float4*)hs)[i] = ((const float4*)(outh + ((size_t)(b * HLEN + HLEN - 1)) * HDIM))[i];
    __syncthreads();
    for (int u = tid; u < HDIM; u += 256) {
        const float4* w1 = (const float4*)(fc1w + (size_t)u * HDIM);
        const float4* w2 = (const float4*)(fc2w + (size_t)u * HDIM);
        float a = 0.f, bacc = 0.f;
        for (int k = 0; k < 128; k++) {
            float4 rv = ((float4*)rs)[k], hv = ((float4*)hs)[k];
            float4 x = w1[k]; a    += rv.x * x.x + rv.y * x.y + rv.z * x.z + rv.w * x.w;
            float4 y = w2[k]; bacc += hv.x * y.x + hv.y * y.y + hv.z * y.z + hv.w * y.w;
        }
        rep[u] = tanhfast(a + fc1b[u] + bacc + fc2b[u]);
    }
    __syncthreads();
    for (int cix = 0; cix < NCLS; cix++) {
        red[tid] = rep[tid] * fc3w[(size_t)cix * HDIM + tid]
                 + rep[tid + 256] * fc3w[(size_t)cix * HDIM + tid + 256];
        __syncthreads();
        for (int off = 128; off; off >>= 1) {
            if (tid < off) red[tid] += red[tid + off];
            __syncthreads();
        }
        if (tid == 0) out[b * NCLS + cix] = red[0] + fc3b[cix];
        __syncthreads();
    }
}

// ---------------------------------------------------------------------------
extern "C" void kernel_launch(void* const* d_in, const int* in_sizes, int n_in,
                              void* d_out, int out_size, void* d_ws, size_t ws_size,
                              hipStream_t stream)
{
    const int*   premise = (const int*)d_in[0];
    const int*   hyp     = (const int*)d_in[1];
    const float* emb     = (const float*)d_in[2];
    const float* Wih1    = (const float*)d_in[3];
    const float* Whh1    = (const float*)d_in[4];
    const float* bih1    = (const float*)d_in[5];
    const float* bhh1    = (const float*)d_in[6];
    const float* Wih2    = (const float*)d_in[7];
    const float* Whh2    = (const float*)d_in[8];
    const float* bih2    = (const float*)d_in[9];
    const float* bhh2    = (const float*)d_in[10];
    const float* Wy      = (const float*)d_in[11];
    const float* Wh      = (const float*)d_in[12];
    const float* Wr      = (const float*)d_in[13];
    const float* Wt      = (const float*)d_in[14];
    const float* wv      = (const float*)d_in[15];
    const float* fc1w    = (const float*)d_in[16];
    const float* fc1b    = (const float*)d_in[17];
    const float* fc2w    = (const float*)d_in[18];
    const float* fc2b    = (const float*)d_in[19];
    const float* fc3w    = (const float*)d_in[20];
    const float* fc3b    = (const float*)d_in[21];
    float* out = (float*)d_out;

    float* ws = (float*)d_ws;
    size_t off = 0;
    float* xp    = ws + off; off += (size_t)BSZ * PLEN * G4;
    float* xh    = ws + off; off += (size_t)BSZ * HLEN * G4;
    float* outp  = ws + off; off += (size_t)BSZ * PLEN * HDIM;
    float* outhp = ws + off; off += (size_t)BSZ * HLEN * HDIM;
    float* a1b   = ws + off; off += (size_t)BSZ * HDIM * PLEN;   // [b][p][h]
    // tagged u64 exchange buffers (contiguous so one zero-kernel covers all).
    // lstm layer-2 h exchange reuses rA/rB (att tags are TOFF-offset).
    unsigned long long* tbase = (unsigned long long*)(ws + off);
    unsigned long long* hAb   = tbase;
    unsigned long long* hBb   = tbase + 32768;            // 64*512
    unsigned long long* a2buf = tbase + 2 * 32768;
    unsigned long long* rAb   = tbase + 3 * 32768;        // also lstm hC
    unsigned long long* rBb   = tbase + 4 * 32768;        // also lstm hD
    unsigned long long* sbuf  = tbase + 5 * 32768;        // 64*128
    off += (size_t)(5 * 32768 + 8192) * 2;                // in floats
    if (ws_size < off * sizeof(float)) return;

    // zero tagged buffers (172032 u64 = 672 * 256)
    ws_zero<<<dim3(672), dim3(256), 0, stream>>>(tbase);

    // input projections (biases folded in): 32x64 tiles
    proj_kernel<<<dim3(BSZ * PLEN / 32, G4 / 64), dim3(256), 0, stream>>>(
        premise, emb, Wih1, bih1, bhh1, xp);
    proj_kernel<<<dim3(BSZ * HLEN / 32, G4 / 64), dim3(256), 0, stream>>>(
        hyp, emb, Wih2, bih2, bhh2, xh);

    // both LSTMs, persistent, tagged-data sync (layer2 h via rA/rB)
    lstm_coop<<<dim3(256), dim3(256), 0, stream>>>(
        xp, xh, Whh1, Whh2, outp, outhp, hAb, hBb, rAb, rBb);

    // a1t = einsum('hj,bpj->bph', Wy, outp)
    a1_kernel<<<dim3(BSZ, PLEN / 32, HDIM / 64), dim3(256), 0, stream>>>(Wy, outp, a1b);

    // attention recurrence, persistent, tagged-data sync
    att_coop<<<dim3(256), dim3(256), 0, stream>>>(
        outhp, a1b, outp, Wh, Wr, Wt, wv, a2buf, sbuf, rAb, rBb);

    // final classifier: r after step 63 lives in rB (63 & 1 == 1)
    final_kernel<<<dim3(BSZ), dim3(256), 0, stream>>>(
        rBb, outhp, fc1w, fc1b, fc2w, fc2b, fc3w, fc3b, out);
}

// Round 7
// 3683.087 us; speedup vs baseline: 3.3536x; 1.0240x over previous
//
#include <hip/hip_runtime.h>
#include <math.h>

#define BSZ 64
#define PLEN 128
#define HLEN 64
#define EDIM 300
#define HDIM 512
#define G4 2048   // 4*HDIM
#define NCLS 3

// att tag offset: lstm layer-2 reuses rA/rB for its h exchange (tags 129..192);
// att tags start at 1000+ so stale lstm tags can never falsely match.
#define TOFF 1000u
// spin guard: protocol bug degrades to wrong answer, not a hung container.
#define SPIN_CAP (1 << 18)

// 16-chunk 512-float vector layout: 16 chunks of 36 floats (32 data + 4 pad).
// float f (0..511) lives at C16(f) = (f>>5)*36 + (f&31). Chunk cc starts at
// 144B (16B-aligned). GEMV read: lane cc reads f4 at word 36cc+4q -> banks
// 4(cc+q)%32: cc and cc+8 alias 2-way (free, m136); float4 spans disjoint.
#define CR16 576
#define C16(f) ((((f) >> 5) * 36) + ((f) & 31))

__device__ __forceinline__ float sigf(float x) { return 1.0f / (1.0f + __expf(-x)); }
__device__ __forceinline__ float tanhfast(float x) { return 1.0f - 2.0f / (__expf(2.0f * x) + 1.0f); }

// relaxed agent-scope atomic helpers: LLC-coherent, no L2 flush/invalidate
__device__ __forceinline__ unsigned long long aload64(const unsigned long long* p) {
    return __hip_atomic_load(p, __ATOMIC_RELAXED, __HIP_MEMORY_SCOPE_AGENT);
}
__device__ __forceinline__ void astore64(unsigned long long* p, unsigned long long v) {
    __hip_atomic_store(p, v, __ATOMIC_RELAXED, __HIP_MEMORY_SCOPE_AGENT);
}
// tagged-value pack: high 32 = step tag, low 32 = float bits.
__device__ __forceinline__ unsigned long long tpack(float v, unsigned tag) {
    return ((unsigned long long)tag << 32) | (unsigned long long)__float_as_uint(v);
}
__device__ __forceinline__ float tval(unsigned long long v) { return __uint_as_float((unsigned)v); }
__device__ __forceinline__ unsigned ttag(unsigned long long v) { return (unsigned)(v >> 32); }

__global__ __launch_bounds__(256) void ws_zero(unsigned long long* p) {
    p[(size_t)blockIdx.x * 256 + threadIdx.x] = 0ull;
}

// ---------------------------------------------------------------------------
// input projection GEMM: out[m][row] = emb[toks[m]] . Wih[row] + bih[row]+bhh[row]
__global__ __launch_bounds__(256) void proj_kernel(
    const int* __restrict__ toks, const float* __restrict__ emb,
    const float* __restrict__ Wih, const float* __restrict__ bih,
    const float* __restrict__ bhh, float* __restrict__ out)
{
    __shared__ float es[32 * 100];
    __shared__ float wsh[64 * 100];
    __shared__ int tks[32];
    const int m0 = blockIdx.x * 32, r0 = blockIdx.y * 64;
    const int tid = threadIdx.x;
    const int tx = tid & 15, ty = tid >> 4;
    float acc[2][4] = {{0.f, 0.f, 0.f, 0.f}, {0.f, 0.f, 0.f, 0.f}};
    if (tid < 32) tks[tid] = toks[m0 + tid];
    __syncthreads();
    for (int kc = 0; kc < 3; kc++) {
        if (kc) __syncthreads();
        for (int i = tid; i < 800; i += 256) {
            int row = i / 25, k4 = i % 25;
            ((float4*)es)[i] = ((const float4*)(emb + (size_t)tks[row] * EDIM + kc * 100))[k4];
        }
        for (int i = tid; i < 1600; i += 256) {
            int row = i / 25, k4 = i % 25;
            ((float4*)wsh)[i] = ((const float4*)(Wih + (size_t)(r0 + row) * EDIM + kc * 100))[k4];
        }
        __syncthreads();
        const float4* e0 = (const float4*)es + ty * 25;
        const float4* e1 = e0 + 16 * 25;
        const float4* w0 = (const float4*)wsh + tx * 25;
#pragma unroll
        for (int k = 0; k < 25; k++) {
            float4 ea = e0[k], eb = e1[k];
#pragma unroll
            for (int j = 0; j < 4; j++) {
                float4 w = w0[k + j * 400];
                acc[0][j] += ea.x * w.x + ea.y * w.y + ea.z * w.z + ea.w * w.w;
                acc[1][j] += eb.x * w.x + eb.y * w.y + eb.z * w.z + eb.w * w.w;
            }
        }
    }
#pragma unroll
    for (int j = 0; j < 4; j++) {
        int rr = r0 + tx + j * 16;
        float bsum = bih[rr] + bhh[rr];
        out[(size_t)(m0 + ty) * G4 + rr]      = acc[0][j] + bsum;
        out[(size_t)(m0 + ty + 16) * G4 + rr] = acc[1][j] + bsum;
    }
}

// ---------------------------------------------------------------------------
// persistent LSTM, tagged-data synced. 256 blocks x 256 threads.
// XCD-local mapping: bg = blockIdx&7, ug = blockIdx>>3.
// GEMV: thread (rq=tid>>4, cc=tid&15) holds 4 rows x K-chunk cc (32 floats):
// each LDS float4 read feeds 16 FMA (4 rows) -> 4x fewer ds_read_b128 than
// the 1-row/4-chunk scheme. Reduce via shfl_xor(1,2,4,8) over the 16 cc lanes.
__global__ __launch_bounds__(256, 1) void lstm_coop(
    const float* __restrict__ xp, const float* __restrict__ xh,
    const float* __restrict__ Whh1, const float* __restrict__ Whh2,
    float* __restrict__ outp, float* __restrict__ outh,
    unsigned long long* __restrict__ hA, unsigned long long* __restrict__ hB,
    unsigned long long* __restrict__ hC, unsigned long long* __restrict__ hD)
{
    const int tid = threadIdx.x;
    const int ug = blockIdx.x >> 3;
    const int bg = blockIdx.x & 7;
    const int u0 = ug * 16, b0 = bg * 8;
    const int rq = tid >> 4, cc = tid & 15;   // 16 row-quads x 16 K-chunks

    __shared__ __align__(16) float hst[8 * CR16];   // 16-chunk h staging
    __shared__ float gsm[64][9];

    float4 w4[32];   // 4 rows x 8 float4 (chunk cc of each row)
#pragma unroll
    for (int j = 0; j < 4; j++) {
        int rr = 4 * rq + j;
        const float4* src = (const float4*)(Whh1 +
            ((size_t)((rr >> 4) * HDIM + u0 + (rr & 15))) * HDIM) + cc * 8;
#pragma unroll
        for (int q = 0; q < 8; q++) w4[j * 8 + q] = src[q];
    }
    float creg = 0.0f;                       // cell state, thread-private (tid<128)
    const int bbc = tid >> 4, uuc = tid & 15;

    for (int t = 0; t < PLEN + HLEN; t++) {
        const int layer2 = (t >= PLEN) ? 1 : 0;
        const int tloc = layer2 ? t - PLEN : t;
        const int T = layer2 ? HLEN : PLEN;
        const float* xproj = layer2 ? xh : xp;
        float* outseq = layer2 ? outh : outp;
        unsigned long long* wA = layer2 ? hC : hA;
        unsigned long long* wB = layer2 ? hD : hB;
        unsigned long long* hwr = (t & 1) ? wB : wA;
        const unsigned long long* hrd = (t & 1) ? wA : wB;

        // prefetch gate pre-activations (latency hides under spin + GEMV)
        float gi = 0.f, gf = 0.f, gg = 0.f, go = 0.f;
        if (tid < 128) {
            size_t xb = ((size_t)(b0 + bbc) * T + tloc) * G4 + u0 + uuc;
            gi = xproj[xb];        gf = xproj[xb + 512];
            gg = xproj[xb + 1024]; go = xproj[xb + 1536];
        }

        if (t == PLEN) {   // reload layer-2 weights into VGPRs (uniform)
#pragma unroll
            for (int j = 0; j < 4; j++) {
                int rr = 4 * rq + j;
                const float4* src = (const float4*)(Whh2 +
                    ((size_t)((rr >> 4) * HDIM + u0 + (rr & 15))) * HDIM) + cc * 8;
#pragma unroll
                for (int q = 0; q < 8; q++) w4[j * 8 + q] = src[q];
            }
        }
        const bool have_h = (tloc != 0);
        if (have_h) {
            // tagged staging, masked re-poll
            const unsigned long long* src = hrd + (size_t)b0 * 512;
            unsigned long long v[16];
            const unsigned expt = (unsigned)t;
#pragma unroll
            for (int i = 0; i < 16; i++) v[i] = aload64(src + tid + i * 256);
            int guard = 0;
            while (true) {
                bool ok = true;
#pragma unroll
                for (int i = 0; i < 16; i++) ok &= (ttag(v[i]) == expt);
                if (__all(ok)) break;
                if (++guard > SPIN_CAP) break;
                __builtin_amdgcn_s_sleep(1);
#pragma unroll
                for (int i = 0; i < 16; i++)
                    if (ttag(v[i]) != expt) v[i] = aload64(src + tid + i * 256);
            }
            __asm__ volatile("" ::: "memory");
#pragma unroll
            for (int i = 0; i < 16; i++) {
                int idx = tid + i * 256;
                int bb = idx >> 9, u = idx & 511;
                hst[bb * CR16 + C16(u)] = tval(v[i]);
            }
            __syncthreads();
            // GEMV: 4 rows/thread, chunk cc; LDS f4 read feeds 16 FMA
#pragma unroll 1
            for (int bb = 0; bb < 8; bb++) {
                const float* hb = &hst[bb * CR16 + cc * 36];
                float a0 = 0.f, a1 = 0.f, a2 = 0.f, a3 = 0.f;
#pragma unroll
                for (int q = 0; q < 8; q++) {
                    float4 hv = *(const float4*)(hb + 4 * q);
                    float4 x;
                    x = w4[q];      a0 += x.x * hv.x + x.y * hv.y + x.z * hv.z + x.w * hv.w;
                    x = w4[8 + q];  a1 += x.x * hv.x + x.y * hv.y + x.z * hv.z + x.w * hv.w;
                    x = w4[16 + q]; a2 += x.x * hv.x + x.y * hv.y + x.z * hv.z + x.w * hv.w;
                    x = w4[24 + q]; a3 += x.x * hv.x + x.y * hv.y + x.z * hv.z + x.w * hv.w;
                }
#pragma unroll
                for (int o = 1; o < 16; o <<= 1) {
                    a0 += __shfl_xor(a0, o);
                    a1 += __shfl_xor(a1, o);
                    a2 += __shfl_xor(a2, o);
                    a3 += __shfl_xor(a3, o);
                }
                if (cc == 0) {
                    gsm[4 * rq + 0][bb] = a0;
                    gsm[4 * rq + 1][bb] = a1;
                    gsm[4 * rq + 2][bb] = a2;
                    gsm[4 * rq + 3][bb] = a3;
                }
            }
        }
        __syncthreads();   // gsm ready; also protects hst vs next staging
        // cell update: thread (bb, uu), tid<128
        if (tid < 128) {
            const int b = b0 + bbc;
            if (have_h) {
                gi += gsm[uuc][bbc];
                gf += gsm[16 + uuc][bbc];
                gg += gsm[32 + uuc][bbc];
                go += gsm[48 + uuc][bbc];
            }
            float cn = sigf(gf) * creg + sigf(gi) * tanhfast(gg);
            float hn = sigf(go) * tanhfast(cn);
            creg = cn;
            astore64(hwr + (size_t)b * 512 + u0 + uuc, tpack(hn, (unsigned)(t + 1)));
            outseq[((size_t)b * T + tloc) * HDIM + u0 + uuc] = hn;
        }
    }
}

// ---------------------------------------------------------------------------
// a1t[b][p][h] = sum_j Wy[h][j] * outp[b][p][j]   (layout [b][p][h])
__global__ __launch_bounds__(256) void a1_kernel(
    const float* __restrict__ Wy, const float* __restrict__ outp,
    float* __restrict__ a1t)
{
    __shared__ float os[32 * 132];
    __shared__ float wsh[64 * 132];
    const int b = blockIdx.x, p0 = blockIdx.y * 32, h0 = blockIdx.z * 64;
    const int tid = threadIdx.x;
    const int tx = tid & 15, ty = tid >> 4;
    float acc[2][4] = {{0.f, 0.f, 0.f, 0.f}, {0.f, 0.f, 0.f, 0.f}};
    for (int kc = 0; kc < 4; kc++) {
        if (kc) __syncthreads();
        for (int i = tid; i < 1024; i += 256) {
            int row = i >> 5, k4 = i & 31;
            ((float4*)os)[row * 33 + k4] =
                ((const float4*)(outp + ((size_t)(b * PLEN) + p0 + row) * HDIM + kc * 128))[k4];
        }
        for (int i = tid; i < 2048; i += 256) {
            int row = i >> 5, k4 = i & 31;
            ((float4*)wsh)[row * 33 + k4] =
                ((const float4*)(Wy + (size_t)(h0 + row) * HDIM + kc * 128))[k4];
        }
        __syncthreads();
        const float4* o0 = (const float4*)os + ty * 33;
        const float4* o1 = o0 + 16 * 33;
        const float4* w0 = (const float4*)wsh + tx * 33;
#pragma unroll
        for (int k = 0; k < 32; k++) {
            float4 ea = o0[k], eb = o1[k];
#pragma unroll
            for (int j = 0; j < 4; j++) {
                float4 w = w0[k + j * 528];
                acc[0][j] += ea.x * w.x + ea.y * w.y + ea.z * w.z + ea.w * w.w;
                acc[1][j] += eb.x * w.x + eb.y * w.y + eb.z * w.z + eb.w * w.w;
            }
        }
    }
#pragma unroll
    for (int j = 0; j < 4; j++) {
        int hh = h0 + tx + j * 16;
        a1t[((size_t)b * PLEN + p0 + ty) * HDIM + hh]      = acc[0][j];
        a1t[((size_t)b * PLEN + p0 + ty + 16) * HDIM + hh] = acc[1][j];
    }
}

// ---------------------------------------------------------------------------
// persistent attention, tagged-data synced (masked re-poll). 256 blocks x 256.
// Phase-A GEMV uses the 4-rows/thread x 16-chunk scheme (rows 48 = 12 quads;
// m = rq>>2 uniform per quad).
#define OSTR 2056   // 128*16 + 8 pad
__global__ __launch_bounds__(256, 1) void att_coop(
    const float* __restrict__ outh, const float* __restrict__ a1b,
    const float* __restrict__ outp,
    const float* __restrict__ Wh, const float* __restrict__ Wr,
    const float* __restrict__ Wt, const float* __restrict__ wv,
    unsigned long long* __restrict__ a2buf, unsigned long long* __restrict__ sbuf,
    unsigned long long* __restrict__ rA, unsigned long long* __restrict__ rB)
{
    const int tid = threadIdx.x;
    const int ug = blockIdx.x >> 3;
    const int bg = blockIdx.x & 7;
    const int u0 = ug * 16, b0 = bg * 8;
    const int rq = tid >> 4, cc = tid & 15;   // row-quad, K-chunk
    const int m = rq >> 2;                    // 0:Wh 1:Wr 2:Wt (rq<12)

    __shared__ __align__(16) float ops[8 * OSTR];    // persistent outp slice
    __shared__ __align__(16) float qa[8 * CR16];     // 16-chunk: q_t (A) / a2 (B)
    __shared__ __align__(16) float rst[8 * CR16];    // 16-chunk r staging
    __shared__ __align__(16) float scst[8][132];
    __shared__ float dsm[48][9];
    __shared__ float tts[16][9];
    __shared__ __align__(16) float wvs[512];

    float4 w4[32];   // 4 rows x 8 f4
    if (rq < 12) {
        const float* W = (m == 0) ? Wh : ((m == 1) ? Wr : Wt);
#pragma unroll
        for (int j = 0; j < 4; j++) {
            int rr = 4 * rq + j;
            const float4* src = (const float4*)(W + (size_t)(u0 + (rr & 15)) * HDIM) + cc * 8;
#pragma unroll
            for (int q = 0; q < 8; q++) w4[j * 8 + q] = src[q];
        }
    }
    for (int i = tid; i < 128; i += 256)
        ((float4*)wvs)[i] = ((const float4*)wv)[i];

    // one-time: outp slice -> LDS
    for (int i = tid; i < 8 * 128 * 4; i += 256) {
        int bb = i >> 9;
        int rem = i & 511;
        int p = rem >> 2, q = rem & 3;
        float4 v = *((const float4*)(outp + ((size_t)(b0 + bb) * PLEN + p) * HDIM + u0) + q);
        *((float4*)(ops + bb * OSTR + p * 16) + q) = v;
    }

    // one-time: a1 slice -> VGPRs
    const int wvid = tid >> 6, lane = tid & 63;
    const int p0g = ug * 4;
    float4 a1r[8][2];
#pragma unroll
    for (int i = 0; i < 8; i++) {
        int pr = wvid * 8 + i;
        int bb = pr >> 2, pp = pr & 3;
        const float4* src = (const float4*)(a1b + ((size_t)(b0 + bb) * PLEN + p0g + pp) * HDIM) + lane;
        a1r[i][0] = src[0];
        a1r[i][1] = src[64];
    }

    const int bbc = tid >> 4, uuc = tid & 15;

    for (int t = 0; t < HLEN; t++) {
        unsigned long long* rwr = (t & 1) ? rB : rA;
        const unsigned long long* rrd = (t & 1) ? rA : rB;

        // ---- phase A: a2 = q.Wh + r.Wr ; tt = tanh(r.Wt)
        for (int i = tid; i < 8 * 128; i += 256) {
            int bb = i >> 7, k4 = i & 127;
            float4 v = ((const float4*)(outh + ((size_t)(b0 + bb) * HLEN + t) * HDIM))[k4];
            *(float4*)&qa[bb * CR16 + (k4 >> 3) * 36 + 4 * (k4 & 7)] = v;
        }
        if (t > 0) {
            const unsigned long long* src = rrd + (size_t)b0 * 512;
            unsigned long long v[16];
            const unsigned expt = TOFF + (unsigned)(3 * t);
#pragma unroll
            for (int i = 0; i < 16; i++) v[i] = aload64(src + tid + i * 256);
            int guard = 0;
            while (true) {
                bool ok = true;
#pragma unroll
                for (int i = 0; i < 16; i++) ok &= (ttag(v[i]) == expt);
                if (__all(ok)) break;
                if (++guard > SPIN_CAP) break;
                __builtin_amdgcn_s_sleep(1);
#pragma unroll
                for (int i = 0; i < 16; i++)
                    if (ttag(v[i]) != expt) v[i] = aload64(src + tid + i * 256);
            }
            __asm__ volatile("" ::: "memory");
#pragma unroll
            for (int i = 0; i < 16; i++) {
                int idx = tid + i * 256;
                int bb = idx >> 9, u = idx & 511;
                rst[bb * CR16 + C16(u)] = tval(v[i]);
            }
        }
        __syncthreads();
        if (rq < 12 && (t > 0 || m == 0)) {
#pragma unroll 1
            for (int bb = 0; bb < 8; bb++) {
                const float* svb = ((m == 0) ? &qa[bb * CR16] : &rst[bb * CR16]) + cc * 36;
                float a0 = 0.f, a1 = 0.f, a2 = 0.f, a3 = 0.f;
#pragma unroll
                for (int q = 0; q < 8; q++) {
                    float4 sv = *(const float4*)(svb + 4 * q);
                    float4 x;
                    x = w4[q];      a0 += x.x * sv.x + x.y * sv.y + x.z * sv.z + x.w * sv.w;
                    x = w4[8 + q];  a1 += x.x * sv.x + x.y * sv.y + x.z * sv.z + x.w * sv.w;
                    x = w4[16 + q]; a2 += x.x * sv.x + x.y * sv.y + x.z * sv.z + x.w * sv.w;
                    x = w4[24 + q]; a3 += x.x * sv.x + x.y * sv.y + x.z * sv.z + x.w * sv.w;
                }
#pragma unroll
                for (int o = 1; o < 16; o <<= 1) {
                    a0 += __shfl_xor(a0, o);
                    a1 += __shfl_xor(a1, o);
                    a2 += __shfl_xor(a2, o);
                    a3 += __shfl_xor(a3, o);
                }
                if (cc == 0) {
                    dsm[4 * rq + 0][bb] = a0;
                    dsm[4 * rq + 1][bb] = a1;
                    dsm[4 * rq + 2][bb] = a2;
                    dsm[4 * rq + 3][bb] = a3;
                }
            }
        }
        __syncthreads();
        if (tid < 128) {
            float aq = dsm[uuc][bbc];
            float ar = (t > 0) ? dsm[16 + uuc][bbc] : 0.0f;
            float at = (t > 0) ? dsm[32 + uuc][bbc] : 0.0f;
            float a2v = aq + ar;
            tts[uuc][bbc] = (t > 0) ? tanhfast(at) : 0.0f;
            astore64(a2buf + (size_t)(b0 + bbc) * 512 + u0 + uuc,
                     tpack(a2v, TOFF + (unsigned)(3 * t + 1)));
        }

        // ---- phase B: s[b][p-slice] = sum_h wv[h]*tanh(a1 + a2)
        {
            const unsigned long long* src = a2buf + (size_t)b0 * 512;
            unsigned long long v[16];
            const unsigned expt = TOFF + (unsigned)(3 * t + 1);
#pragma unroll
            for (int i = 0; i < 16; i++) v[i] = aload64(src + tid + i * 256);
            int guard = 0;
            while (true) {
                bool ok = true;
#pragma unroll
                for (int i = 0; i < 16; i++) ok &= (ttag(v[i]) == expt);
                if (__all(ok)) break;
                if (++guard > SPIN_CAP) break;
                __builtin_amdgcn_s_sleep(1);
#pragma unroll
                for (int i = 0; i < 16; i++)
                    if (ttag(v[i]) != expt) v[i] = aload64(src + tid + i * 256);
            }
            __asm__ volatile("" ::: "memory");
#pragma unroll
            for (int i = 0; i < 16; i++) {
                int idx = tid + i * 256;
                int bb = idx >> 9, u = idx & 511;
                qa[bb * CR16 + C16(u)] = tval(v[i]);
            }
        }
        __syncthreads();
        {
#pragma unroll 2
            for (int i = 0; i < 8; i++) {
                int pr = wvid * 8 + i;
                int bb = pr >> 2, pp = pr & 3;
                float s = 0.f;
#pragma unroll
                for (int k = 0; k < 2; k++) {
                    int h4 = lane + 64 * k;
                    float4 av = a1r[i][k];
                    float4 a2v = *(const float4*)&qa[bb * CR16 + (h4 >> 3) * 36 + 4 * (h4 & 7)];
                    float4 wv4 = ((const float4*)wvs)[h4];
                    s += wv4.x * tanhfast(av.x + a2v.x)
                       + wv4.y * tanhfast(av.y + a2v.y)
                       + wv4.z * tanhfast(av.z + a2v.z)
                       + wv4.w * tanhfast(av.w + a2v.w);
                }
#pragma unroll
                for (int o = 1; o < 64; o <<= 1) s += __shfl_xor(s, o);
                if (lane == 0)
                    astore64(sbuf + (size_t)(b0 + bb) * PLEN + p0g + pp,
                             tpack(s, TOFF + (unsigned)(3 * t + 2)));
            }
        }

        // ---- phase C: softmax over p (redundant per block) + r update
        {
            const unsigned long long* src = sbuf + (size_t)b0 * 128;
            unsigned long long v[4];
            const unsigned expt = TOFF + (unsigned)(3 * t + 2);
#pragma unroll
            for (int i = 0; i < 4; i++) v[i] = aload64(src + tid + i * 256);
            int guard = 0;
            while (true) {
                bool ok = true;
#pragma unroll
                for (int i = 0; i < 4; i++) ok &= (ttag(v[i]) == expt);
                if (__all(ok)) break;
                if (++guard > SPIN_CAP) break;
                __builtin_amdgcn_s_sleep(1);
#pragma unroll
                for (int i = 0; i < 4; i++)
                    if (ttag(v[i]) != expt) v[i] = aload64(src + tid + i * 256);
            }
            __asm__ volatile("" ::: "memory");
#pragma unroll
            for (int i = 0; i < 4; i++) {
                int idx = tid + i * 256;
                int bb = idx >> 7, j = idx & 127;
                scst[bb][j] = tval(v[i]);
            }
        }
        __syncthreads();
        {
            const int bb = tid >> 5, j = tid & 31;
            float4 v = *(float4*)&scst[bb][j * 4];
            float mx = fmaxf(fmaxf(v.x, v.y), fmaxf(v.z, v.w));
#pragma unroll
            for (int o = 1; o < 32; o <<= 1) mx = fmaxf(mx, __shfl_xor(mx, o));
            float ex = __expf(v.x - mx), ey = __expf(v.y - mx);
            float ez = __expf(v.z - mx), ew = __expf(v.w - mx);
            float ssum = (ex + ey) + (ez + ew);
#pragma unroll
            for (int o = 1; o < 32; o <<= 1) ssum += __shfl_xor(ssum, o);
            float inv = 1.0f / ssum;
            float4 sc4 = make_float4(ex * inv, ey * inv, ez * inv, ew * inv);
            *(float4*)&scst[bb][j * 4] = sc4;
        }
        __syncthreads();
        if (tid < 128) {
            float acc = tts[uuc][bbc];
            const float* opb = ops + bbc * OSTR + uuc;
#pragma unroll 8
            for (int p = 0; p < PLEN; p++)
                acc += scst[bbc][p] * opb[p * 16];
            astore64(rwr + (size_t)(b0 + bbc) * 512 + u0 + uuc,
                     tpack(acc, TOFF + (unsigned)(3 * t + 3)));
        }
    }
}

// ---------------------------------------------------------------------------
// final: rep = tanh(r.fc1^T + b1 + hn.fc2^T + b2); out = rep.fc3^T + b3
__global__ __launch_bounds__(256) void final_kernel(
    const unsigned long long* __restrict__ r2, const float* __restrict__ outh,
    const float* __restrict__ fc1w, const float* __restrict__ fc1b,
    const float* __restrict__ fc2w, const float* __restrict__ fc2b,
    const float* __restrict__ fc3w, const float* __restrict__ fc3b,
    float* __restrict__ out)
{
    int b = blockIdx.x, tid = threadIdx.x;
    __shared__ float rs[HDIM], hs[HDIM], rep[HDIM], red[256];
    for (int i = tid; i < 512; i += 256)
        rs[i] = tval(r2[(size_t)b * 512 + i]);
    for (int i = tid; i < 128; i += 256)
        ((float4*)hs)[i] = ((const float4*)(outh + ((size_t)(b * HLEN + HLEN - 1)) * HDIM))[i];
    __syncthreads();
    for (int u = tid; u < HDIM; u += 256) {
        const float4* w1 = (const float4*)(fc1w + (size_t)u * HDIM);
        const float4* w2 = (const float4*)(fc2w + (size_t)u * HDIM);
        float a = 0.f, bacc = 0.f;
        for (int k = 0; k < 128; k++) {
            float4 rv = ((float4*)rs)[k], hv = ((float4*)hs)[k];
            float4 x = w1[k]; a    += rv.x * x.x + rv.y * x.y + rv.z * x.z + rv.w * x.w;
            float4 y = w2[k]; bacc += hv.x * y.x + hv.y * y.y + hv.z * y.z + hv.w * y.w;
        }
        rep[u] = tanhfast(a + fc1b[u] + bacc + fc2b[u]);
    }
    __syncthreads();
    for (int cix = 0; cix < NCLS; cix++) {
        red[tid] = rep[tid] * fc3w[(size_t)cix * HDIM + tid]
                 + rep[tid + 256] * fc3w[(size_t)cix * HDIM + tid + 256];
        __syncthreads();
        for (int off = 128; off; off >>= 1) {
            if (tid < off) red[tid] += red[tid + off];
            __syncthreads();
        }
        if (tid == 0) out[b * NCLS + cix] = red[0] + fc3b[cix];
        __syncthreads();
    }
}

// ---------------------------------------------------------------------------
extern "C" void kernel_launch(void* const* d_in, const int* in_sizes, int n_in,
                              void* d_out, int out_size, void* d_ws, size_t ws_size,
                              hipStream_t stream)
{
    const int*   premise = (const int*)d_in[0];
    const int*   hyp     = (const int*)d_in[1];
    const float* emb     = (const float*)d_in[2];
    const float* Wih1    = (const float*)d_in[3];
    const float* Whh1    = (const float*)d_in[4];
    const float* bih1    = (const float*)d_in[5];
    const float* bhh1    = (const float*)d_in[6];
    const float* Wih2    = (const float*)d_in[7];
    const float* Whh2    = (const float*)d_in[8];
    const float* bih2    = (const float*)d_in[9];
    const float* bhh2    = (const float*)d_in[10];
    const float* Wy      = (const float*)d_in[11];
    const float* Wh      = (const float*)d_in[12];
    const float* Wr      = (const float*)d_in[13];
    const float* Wt      = (const float*)d_in[14];
    const float* wv      = (const float*)d_in[15];
    const float* fc1w    = (const float*)d_in[16];
    const float* fc1b    = (const float*)d_in[17];
    const float* fc2w    = (const float*)d_in[18];
    const float* fc2b    = (const float*)d_in[19];
    const float* fc3w    = (const float*)d_in[20];
    const float* fc3b    = (const float*)d_in[21];
    float* out = (float*)d_out;

    float* ws = (float*)d_ws;
    size_t off = 0;
    float* xp    = ws + off; off += (size_t)BSZ * PLEN * G4;
    float* xh    = ws + off; off += (size_t)BSZ * HLEN * G4;
    float* outp  = ws + off; off += (size_t)BSZ * PLEN * HDIM;
    float* outhp = ws + off; off += (size_t)BSZ * HLEN * HDIM;
    float* a1b   = ws + off; off += (size_t)BSZ * HDIM * PLEN;   // [b][p][h]
    // tagged u64 exchange buffers (contiguous so one zero-kernel covers all).
    // lstm layer-2 h exchange reuses rA/rB (att tags are TOFF-offset).
    unsigned long long* tbase = (unsigned long long*)(ws + off);
    unsigned long long* hAb   = tbase;
    unsigned long long* hBb   = tbase + 32768;            // 64*512
    unsigned long long* a2buf = tbase + 2 * 32768;
    unsigned long long* rAb   = tbase + 3 * 32768;        // also lstm hC
    unsigned long long* rBb   = tbase + 4 * 32768;        // also lstm hD
    unsigned long long* sbuf  = tbase + 5 * 32768;        // 64*128
    off += (size_t)(5 * 32768 + 8192) * 2;                // in floats
    if (ws_size < off * sizeof(float)) return;

    // zero tagged buffers (172032 u64 = 672 * 256)
    ws_zero<<<dim3(672), dim3(256), 0, stream>>>(tbase);

    // input projections (biases folded in): 32x64 tiles
    proj_kernel<<<dim3(BSZ * PLEN / 32, G4 / 64), dim3(256), 0, stream>>>(
        premise, emb, Wih1, bih1, bhh1, xp);
    proj_kernel<<<dim3(BSZ * HLEN / 32, G4 / 64), dim3(256), 0, stream>>>(
        hyp, emb, Wih2, bih2, bhh2, xh);

    // both LSTMs, persistent, tagged-data sync (layer2 h via rA/rB)
    lstm_coop<<<dim3(256), dim3(256), 0, stream>>>(
        xp, xh, Whh1, Whh2, outp, outhp, hAb, hBb, rAb, rBb);

    // a1t = einsum('hj,bpj->bph', Wy, outp)
    a1_kernel<<<dim3(BSZ, PLEN / 32, HDIM / 64), dim3(256), 0, stream>>>(Wy, outp, a1b);

    // attention recurrence, persistent, tagged-data sync
    att_coop<<<dim3(256), dim3(256), 0, stream>>>(
        outhp, a1b, outp, Wh, Wr, Wt, wv, a2buf, sbuf, rAb, rBb);

    // final classifier: r after step 63 lives in rB (63 & 1 == 1)
    final_kernel<<<dim3(BSZ), dim3(256), 0, stream>>>(
        rBb, outhp, fc1w, fc1b, fc2w, fc2b, fc3w, fc3b, out);
}

// Round 8
// 3442.292 us; speedup vs baseline: 3.5882x; 1.0700x over previous
//
#include <hip/hip_runtime.h>
#include <math.h>

#define BSZ 64
#define PLEN 128
#define HLEN 64
#define EDIM 300
#define HDIM 512
#define G4 2048   // 4*HDIM
#define NCLS 3

// att done-tags start at 1000+ (monotone, > any lstm tag 1..192).
#define TOFF 1000u
// spin guard: protocol bug degrades to wrong answer, not a hung container.
#define SPIN_CAP (1 << 18)

// 16-chunk 512-float vector layout: 16 chunks of 36 floats (32 data + 4 pad).
// float f (0..511) lives at C16(f) = (f>>5)*36 + (f&31). GEMV read: lane cc
// reads f4 at word 36cc+4q -> banks 4(cc+q)%32: cc/cc+8 alias 2-way (free).
#define CR16 576
#define C16(f) ((((f) >> 5) * 36) + ((f) & 31))

__device__ __forceinline__ float sigf(float x) { return 1.0f / (1.0f + __expf(-x)); }
__device__ __forceinline__ float tanhfast(float x) { return 1.0f - 2.0f / (__expf(2.0f * x) + 1.0f); }

// relaxed agent-scope atomics: LLC-coherent, bypass non-coherent L1/L2
__device__ __forceinline__ unsigned long long aload64(const unsigned long long* p) {
    return __hip_atomic_load(p, __ATOMIC_RELAXED, __HIP_MEMORY_SCOPE_AGENT);
}
__device__ __forceinline__ void astore64(unsigned long long* p, unsigned long long v) {
    __hip_atomic_store(p, v, __ATOMIC_RELAXED, __HIP_MEMORY_SCOPE_AGENT);
}
__device__ __forceinline__ unsigned long long fpack2(float lo, float hi) {
    float2 v = make_float2(lo, hi);
    return *(unsigned long long*)&v;
}
__device__ __forceinline__ float2 funpack2(unsigned long long u) {
    union { unsigned long long u; float2 f; } c; c.u = u; return c.f;
}

// DONE-WORD PROTOCOL: producer stores plain packed data, drains vmcnt,
// barrier, then ONE u64 done-word = step tag (monotone). Consumer: lanes
// 0-31 poll the 32 done-words with >= (256B/round, ~1000x less poll traffic
// than polling the data), then load data once -- guaranteed complete at LLC.
// Safety: >= cannot deadlock on overwrites (tags only grow); data-buffer
// reuse is >=2 steps apart while producer-consumer skew is <=1 step (same
// induction as the tagged scheme, R4).

__global__ __launch_bounds__(256) void ws_zero(unsigned long long* p) {
    p[(size_t)blockIdx.x * 256 + threadIdx.x] = 0ull;
}

// ---------------------------------------------------------------------------
// input projection GEMM: out[m][row] = emb[toks[m]] . Wih[row] + bih[row]+bhh[row]
__global__ __launch_bounds__(256) void proj_kernel(
    const int* __restrict__ toks, const float* __restrict__ emb,
    const float* __restrict__ Wih, const float* __restrict__ bih,
    const float* __restrict__ bhh, float* __restrict__ out)
{
    __shared__ float es[32 * 100];
    __shared__ float wsh[64 * 100];
    __shared__ int tks[32];
    const int m0 = blockIdx.x * 32, r0 = blockIdx.y * 64;
    const int tid = threadIdx.x;
    const int tx = tid & 15, ty = tid >> 4;
    float acc[2][4] = {{0.f, 0.f, 0.f, 0.f}, {0.f, 0.f, 0.f, 0.f}};
    if (tid < 32) tks[tid] = toks[m0 + tid];
    __syncthreads();
    for (int kc = 0; kc < 3; kc++) {
        if (kc) __syncthreads();
        for (int i = tid; i < 800; i += 256) {
            int row = i / 25, k4 = i % 25;
            ((float4*)es)[i] = ((const float4*)(emb + (size_t)tks[row] * EDIM + kc * 100))[k4];
        }
        for (int i = tid; i < 1600; i += 256) {
            int row = i / 25, k4 = i % 25;
            ((float4*)wsh)[i] = ((const float4*)(Wih + (size_t)(r0 + row) * EDIM + kc * 100))[k4];
        }
        __syncthreads();
        const float4* e0 = (const float4*)es + ty * 25;
        const float4* e1 = e0 + 16 * 25;
        const float4* w0 = (const float4*)wsh + tx * 25;
#pragma unroll
        for (int k = 0; k < 25; k++) {
            float4 ea = e0[k], eb = e1[k];
#pragma unroll
            for (int j = 0; j < 4; j++) {
                float4 w = w0[k + j * 400];
                acc[0][j] += ea.x * w.x + ea.y * w.y + ea.z * w.z + ea.w * w.w;
                acc[1][j] += eb.x * w.x + eb.y * w.y + eb.z * w.z + eb.w * w.w;
            }
        }
    }
#pragma unroll
    for (int j = 0; j < 4; j++) {
        int rr = r0 + tx + j * 16;
        float bsum = bih[rr] + bhh[rr];
        out[(size_t)(m0 + ty) * G4 + rr]      = acc[0][j] + bsum;
        out[(size_t)(m0 + ty + 16) * G4 + rr] = acc[1][j] + bsum;
    }
}

// ---------------------------------------------------------------------------
// persistent LSTM, done-word synced. 256 blocks x 256 threads.
// XCD-local: bg = blockIdx&7, ug = blockIdx>>3. Layer 2 uses hC/hD (R4 fix).
// h data: packed float2 u64, 256 u64/batch. done tag after step t = t+1.
__global__ __launch_bounds__(256, 1) void lstm_coop(
    const float* __restrict__ xp, const float* __restrict__ xh,
    const float* __restrict__ Whh1, const float* __restrict__ Whh2,
    float* __restrict__ outp, float* __restrict__ outh,
    unsigned long long* __restrict__ hA, unsigned long long* __restrict__ hB,
    unsigned long long* __restrict__ hC, unsigned long long* __restrict__ hD,
    unsigned long long* __restrict__ doneH)
{
    const int tid = threadIdx.x;
    const int ug = blockIdx.x >> 3;
    const int bg = blockIdx.x & 7;
    const int u0 = ug * 16, b0 = bg * 8;
    const int rq = tid >> 4, cc = tid & 15;   // 16 row-quads x 16 K-chunks

    __shared__ __align__(16) float hst[8 * CR16];   // 16-chunk h staging
    __shared__ float gsm[64][9];

    float4 w4[32];   // 4 rows x 8 float4 (chunk cc of each row)
#pragma unroll
    for (int j = 0; j < 4; j++) {
        int rr = 4 * rq + j;
        const float4* src = (const float4*)(Whh1 +
            ((size_t)((rr >> 4) * HDIM + u0 + (rr & 15))) * HDIM) + cc * 8;
#pragma unroll
        for (int q = 0; q < 8; q++) w4[j * 8 + q] = src[q];
    }
    float creg = 0.0f;                       // cell state, thread-private (tid<128)
    const int bbc = tid >> 4, uuc = tid & 15;
    unsigned long long* dn = doneH + bg * 32;

    for (int t = 0; t < PLEN + HLEN; t++) {
        const int layer2 = (t >= PLEN) ? 1 : 0;
        const int tloc = layer2 ? t - PLEN : t;
        const int T = layer2 ? HLEN : PLEN;
        const float* xproj = layer2 ? xh : xp;
        float* outseq = layer2 ? outh : outp;
        unsigned long long* wA = layer2 ? hC : hA;
        unsigned long long* wB = layer2 ? hD : hB;
        unsigned long long* hwr = (t & 1) ? wB : wA;
        const unsigned long long* hrd = (t & 1) ? wA : wB;

        // prefetch gate pre-activations (latency hides under poll + GEMV)
        float gi = 0.f, gf = 0.f, gg = 0.f, go = 0.f;
        if (tid < 128) {
            size_t xb = ((size_t)(b0 + bbc) * T + tloc) * G4 + u0 + uuc;
            gi = xproj[xb];        gf = xproj[xb + 512];
            gg = xproj[xb + 1024]; go = xproj[xb + 1536];
        }

        if (t == PLEN) {   // reload layer-2 weights into VGPRs (uniform)
#pragma unroll
            for (int j = 0; j < 4; j++) {
                int rr = 4 * rq + j;
                const float4* src = (const float4*)(Whh2 +
                    ((size_t)((rr >> 4) * HDIM + u0 + (rr & 15))) * HDIM) + cc * 8;
#pragma unroll
                for (int q = 0; q < 8; q++) w4[j * 8 + q] = src[q];
            }
        }
        const bool have_h = (tloc != 0);
        if (have_h) {
            // done-word poll: lanes 0..31 only, 256B/round
            if (tid < 32) {
                unsigned long long v = aload64(dn + tid);
                int guard = 0;
                while (!__all(v >= (unsigned long long)t)) {
                    if (++guard > SPIN_CAP) break;
                    __builtin_amdgcn_s_sleep(1);
                    if (v < (unsigned long long)t) v = aload64(dn + tid);
                }
            }
            __syncthreads();
            __asm__ volatile("" ::: "memory");
            // data load: ONE round, 8 u64/thread (8 batches x 256 u64)
            const unsigned long long* src = hrd + (size_t)b0 * 256;
            unsigned long long v[8];
#pragma unroll
            for (int i = 0; i < 8; i++) v[i] = aload64(src + tid + i * 256);
#pragma unroll
            for (int i = 0; i < 8; i++) {
                int idx = tid + i * 256;
                int bb = idx >> 8, j = idx & 255;
                float2 f = funpack2(v[i]);
                *(float2*)&hst[bb * CR16 + C16(2 * j)] = f;
            }
            __syncthreads();
            // GEMV: 4 rows/thread, chunk cc; LDS f4 read feeds 16 FMA
#pragma unroll 1
            for (int bb = 0; bb < 8; bb++) {
                const float* hb = &hst[bb * CR16 + cc * 36];
                float a0 = 0.f, a1 = 0.f, a2 = 0.f, a3 = 0.f;
#pragma unroll
                for (int q = 0; q < 8; q++) {
                    float4 hv = *(const float4*)(hb + 4 * q);
                    float4 x;
                    x = w4[q];      a0 += x.x * hv.x + x.y * hv.y + x.z * hv.z + x.w * hv.w;
                    x = w4[8 + q];  a1 += x.x * hv.x + x.y * hv.y + x.z * hv.z + x.w * hv.w;
                    x = w4[16 + q]; a2 += x.x * hv.x + x.y * hv.y + x.z * hv.z + x.w * hv.w;
                    x = w4[24 + q]; a3 += x.x * hv.x + x.y * hv.y + x.z * hv.z + x.w * hv.w;
                }
#pragma unroll
                for (int o = 1; o < 16; o <<= 1) {
                    a0 += __shfl_xor(a0, o);
                    a1 += __shfl_xor(a1, o);
                    a2 += __shfl_xor(a2, o);
                    a3 += __shfl_xor(a3, o);
                }
                if (cc == 0) {
                    gsm[4 * rq + 0][bb] = a0;
                    gsm[4 * rq + 1][bb] = a1;
                    gsm[4 * rq + 2][bb] = a2;
                    gsm[4 * rq + 3][bb] = a3;
                }
            }
        }
        __syncthreads();   // gsm ready; protects hst vs next staging
        // cell update: thread (bb, uu), tid<128
        float hn = 0.f;
        if (tid < 128) {
            if (have_h) {
                gi += gsm[uuc][bbc];
                gf += gsm[16 + uuc][bbc];
                gg += gsm[32 + uuc][bbc];
                go += gsm[48 + uuc][bbc];
            }
            float cn = sigf(gf) * creg + sigf(gi) * tanhfast(gg);
            hn = sigf(go) * tanhfast(cn);
            creg = cn;
            float pr = __shfl_xor(hn, 1);
            if ((uuc & 1) == 0)
                astore64(hwr + (size_t)(b0 + bbc) * 256 + (u0 + uuc) / 2, fpack2(hn, pr));
        }
        // drain h stores, then publish done (one u64), then off-path outseq
        __asm__ volatile("s_waitcnt vmcnt(0)" ::: "memory");
        __syncthreads();
        if (tid == 0) astore64(&dn[ug], (unsigned long long)(t + 1));
        if (tid < 128)
            outseq[((size_t)(b0 + bbc) * T + tloc) * HDIM + u0 + uuc] = hn;
    }
}

// ---------------------------------------------------------------------------
// a1t[b][p][h] = sum_j Wy[h][j] * outp[b][p][j]   (layout [b][p][h])
__global__ __launch_bounds__(256) void a1_kernel(
    const float* __restrict__ Wy, const float* __restrict__ outp,
    float* __restrict__ a1t)
{
    __shared__ float os[32 * 132];
    __shared__ float wsh[64 * 132];
    const int b = blockIdx.x, p0 = blockIdx.y * 32, h0 = blockIdx.z * 64;
    const int tid = threadIdx.x;
    const int tx = tid & 15, ty = tid >> 4;
    float acc[2][4] = {{0.f, 0.f, 0.f, 0.f}, {0.f, 0.f, 0.f, 0.f}};
    for (int kc = 0; kc < 4; kc++) {
        if (kc) __syncthreads();
        for (int i = tid; i < 1024; i += 256) {
            int row = i >> 5, k4 = i & 31;
            ((float4*)os)[row * 33 + k4] =
                ((const float4*)(outp + ((size_t)(b * PLEN) + p0 + row) * HDIM + kc * 128))[k4];
        }
        for (int i = tid; i < 2048; i += 256) {
            int row = i >> 5, k4 = i & 31;
            ((float4*)wsh)[row * 33 + k4] =
                ((const float4*)(Wy + (size_t)(h0 + row) * HDIM + kc * 128))[k4];
        }
        __syncthreads();
        const float4* o0 = (const float4*)os + ty * 33;
        const float4* o1 = o0 + 16 * 33;
        const float4* w0 = (const float4*)wsh + tx * 33;
#pragma unroll
        for (int k = 0; k < 32; k++) {
            float4 ea = o0[k], eb = o1[k];
#pragma unroll
            for (int j = 0; j < 4; j++) {
                float4 w = w0[k + j * 528];
                acc[0][j] += ea.x * w.x + ea.y * w.y + ea.z * w.z + ea.w * w.w;
                acc[1][j] += eb.x * w.x + eb.y * w.y + eb.z * w.z + eb.w * w.w;
            }
        }
    }
#pragma unroll
    for (int j = 0; j < 4; j++) {
        int hh = h0 + tx + j * 16;
        a1t[((size_t)b * PLEN + p0 + ty) * HDIM + hh]      = acc[0][j];
        a1t[((size_t)b * PLEN + p0 + ty + 16) * HDIM + hh] = acc[1][j];
    }
}

// ---------------------------------------------------------------------------
// persistent attention, done-word synced. 256 blocks x 256 threads.
// Tags: doneA = TOFF+3t+1, doneB = TOFF+3t+2, doneC = TOFF+3t+3 (monotone).
#define OSTR 2056   // 128*16 + 8 pad
__global__ __launch_bounds__(256, 1) void att_coop(
    const float* __restrict__ outh, const float* __restrict__ a1b,
    const float* __restrict__ outp,
    const float* __restrict__ Wh, const float* __restrict__ Wr,
    const float* __restrict__ Wt, const float* __restrict__ wv,
    unsigned long long* __restrict__ a2buf, unsigned long long* __restrict__ sbuf,
    unsigned long long* __restrict__ rA, unsigned long long* __restrict__ rB,
    unsigned long long* __restrict__ doneA, unsigned long long* __restrict__ doneB,
    unsigned long long* __restrict__ doneC)
{
    const int tid = threadIdx.x;
    const int ug = blockIdx.x >> 3;
    const int bg = blockIdx.x & 7;
    const int u0 = ug * 16, b0 = bg * 8;
    const int rq = tid >> 4, cc = tid & 15;   // row-quad, K-chunk
    const int m = rq >> 2;                    // 0:Wh 1:Wr 2:Wt (rq<12)

    __shared__ __align__(16) float ops[8 * OSTR];    // persistent outp slice
    __shared__ __align__(16) float qa[8 * CR16];     // 16-chunk: q_t (A) / a2 (B)
    __shared__ __align__(16) float rst[8 * CR16];    // 16-chunk r staging
    __shared__ __align__(16) float scst[8][132];
    __shared__ float dsm[48][9];
    __shared__ float tts[16][9];
    __shared__ __align__(16) float wvs[512];

    float4 w4[32];   // 4 rows x 8 f4
    if (rq < 12) {
        const float* W = (m == 0) ? Wh : ((m == 1) ? Wr : Wt);
#pragma unroll
        for (int j = 0; j < 4; j++) {
            int rr = 4 * rq + j;
            const float4* src = (const float4*)(W + (size_t)(u0 + (rr & 15)) * HDIM) + cc * 8;
#pragma unroll
            for (int q = 0; q < 8; q++) w4[j * 8 + q] = src[q];
        }
    }
    for (int i = tid; i < 128; i += 256)
        ((float4*)wvs)[i] = ((const float4*)wv)[i];

    // one-time: outp slice -> LDS
    for (int i = tid; i < 8 * 128 * 4; i += 256) {
        int bb = i >> 9;
        int rem = i & 511;
        int p = rem >> 2, q = rem & 3;
        float4 v = *((const float4*)(outp + ((size_t)(b0 + bb) * PLEN + p) * HDIM + u0) + q);
        *((float4*)(ops + bb * OSTR + p * 16) + q) = v;
    }

    // one-time: a1 slice -> VGPRs
    const int wvid = tid >> 6, lane = tid & 63;
    const int p0g = ug * 4;
    float4 a1r[8][2];
#pragma unroll
    for (int i = 0; i < 8; i++) {
        int pr = wvid * 8 + i;
        int bb = pr >> 2, pp = pr & 3;
        const float4* src = (const float4*)(a1b + ((size_t)(b0 + bb) * PLEN + p0g + pp) * HDIM) + lane;
        a1r[i][0] = src[0];
        a1r[i][1] = src[64];
    }

    unsigned long long* dnA = doneA + bg * 32;
    unsigned long long* dnB = doneB + bg * 32;
    unsigned long long* dnC = doneC + bg * 32;
    const int bbc = tid >> 4, uuc = tid & 15;

    for (int t = 0; t < HLEN; t++) {
        unsigned long long* rwr = (t & 1) ? rB : rA;
        const unsigned long long* rrd = (t & 1) ? rA : rB;

        // ---- phase A: a2 = q.Wh + r.Wr ; tt = tanh(r.Wt)
        for (int i = tid; i < 8 * 128; i += 256) {
            int bb = i >> 7, k4 = i & 127;
            float4 v = ((const float4*)(outh + ((size_t)(b0 + bb) * HLEN + t) * HDIM))[k4];
            *(float4*)&qa[bb * CR16 + (k4 >> 3) * 36 + 4 * (k4 & 7)] = v;
        }
        if (t > 0) {
            const unsigned long long expt = TOFF + (unsigned long long)(3 * t);
            if (tid < 32) {
                unsigned long long v = aload64(dnC + tid);
                int guard = 0;
                while (!__all(v >= expt)) {
                    if (++guard > SPIN_CAP) break;
                    __builtin_amdgcn_s_sleep(1);
                    if (v < expt) v = aload64(dnC + tid);
                }
            }
            __syncthreads();
            __asm__ volatile("" ::: "memory");
            const unsigned long long* src = rrd + (size_t)b0 * 256;
            unsigned long long v[8];
#pragma unroll
            for (int i = 0; i < 8; i++) v[i] = aload64(src + tid + i * 256);
#pragma unroll
            for (int i = 0; i < 8; i++) {
                int idx = tid + i * 256;
                int bb = idx >> 8, j = idx & 255;
                float2 f = funpack2(v[i]);
                *(float2*)&rst[bb * CR16 + C16(2 * j)] = f;
            }
        }
        __syncthreads();
        if (rq < 12 && (t > 0 || m == 0)) {
#pragma unroll 1
            for (int bb = 0; bb < 8; bb++) {
                const float* svb = ((m == 0) ? &qa[bb * CR16] : &rst[bb * CR16]) + cc * 36;
                float a0 = 0.f, a1 = 0.f, a2 = 0.f, a3 = 0.f;
#pragma unroll
                for (int q = 0; q < 8; q++) {
                    float4 sv = *(const float4*)(svb + 4 * q);
                    float4 x;
                    x = w4[q];      a0 += x.x * sv.x + x.y * sv.y + x.z * sv.z + x.w * sv.w;
                    x = w4[8 + q];  a1 += x.x * sv.x + x.y * sv.y + x.z * sv.z + x.w * sv.w;
                    x = w4[16 + q]; a2 += x.x * sv.x + x.y * sv.y + x.z * sv.z + x.w * sv.w;
                    x = w4[24 + q]; a3 += x.x * sv.x + x.y * sv.y + x.z * sv.z + x.w * sv.w;
                }
#pragma unroll
                for (int o = 1; o < 16; o <<= 1) {
                    a0 += __shfl_xor(a0, o);
                    a1 += __shfl_xor(a1, o);
                    a2 += __shfl_xor(a2, o);
                    a3 += __shfl_xor(a3, o);
                }
                if (cc == 0) {
                    dsm[4 * rq + 0][bb] = a0;
                    dsm[4 * rq + 1][bb] = a1;
                    dsm[4 * rq + 2][bb] = a2;
                    dsm[4 * rq + 3][bb] = a3;
                }
            }
        }
        __syncthreads();
        if (tid < 128) {
            float aq = dsm[uuc][bbc];
            float ar = (t > 0) ? dsm[16 + uuc][bbc] : 0.0f;
            float at = (t > 0) ? dsm[32 + uuc][bbc] : 0.0f;
            float a2v = aq + ar;
            tts[uuc][bbc] = (t > 0) ? tanhfast(at) : 0.0f;
            float pr = __shfl_xor(a2v, 1);
            if ((uuc & 1) == 0)
                astore64(a2buf + (size_t)(b0 + bbc) * 256 + (u0 + uuc) / 2, fpack2(a2v, pr));
        }
        __asm__ volatile("s_waitcnt vmcnt(0)" ::: "memory");
        __syncthreads();
        if (tid == 0) astore64(&dnA[ug], TOFF + (unsigned long long)(3 * t + 1));

        // ---- phase B: s[b][p-slice] = sum_h wv[h]*tanh(a1 + a2)
        {
            const unsigned long long expt = TOFF + (unsigned long long)(3 * t + 1);
            if (tid < 32) {
                unsigned long long v = aload64(dnA + tid);
                int guard = 0;
                while (!__all(v >= expt)) {
                    if (++guard > SPIN_CAP) break;
                    __builtin_amdgcn_s_sleep(1);
                    if (v < expt) v = aload64(dnA + tid);
                }
            }
            __syncthreads();
            __asm__ volatile("" ::: "memory");
            const unsigned long long* src = a2buf + (size_t)b0 * 256;
            unsigned long long v[8];
#pragma unroll
            for (int i = 0; i < 8; i++) v[i] = aload64(src + tid + i * 256);
#pragma unroll
            for (int i = 0; i < 8; i++) {
                int idx = tid + i * 256;
                int bb = idx >> 8, j = idx & 255;
                float2 f = funpack2(v[i]);
                *(float2*)&qa[bb * CR16 + C16(2 * j)] = f;
            }
        }
        __syncthreads();
        {
            float s8[8];
#pragma unroll 2
            for (int i = 0; i < 8; i++) {
                int pr = wvid * 8 + i;
                int bb = pr >> 2;
                float s = 0.f;
#pragma unroll
                for (int k = 0; k < 2; k++) {
                    int h4 = lane + 64 * k;
                    float4 av = a1r[i][k];
                    float4 a2v = *(const float4*)&qa[bb * CR16 + (h4 >> 3) * 36 + 4 * (h4 & 7)];
                    float4 wv4 = ((const float4*)wvs)[h4];
                    s += wv4.x * tanhfast(av.x + a2v.x)
                       + wv4.y * tanhfast(av.y + a2v.y)
                       + wv4.z * tanhfast(av.z + a2v.z)
                       + wv4.w * tanhfast(av.w + a2v.w);
                }
#pragma unroll
                for (int o = 1; o < 64; o <<= 1) s += __shfl_xor(s, o);
                s8[i] = s;
            }
            if (lane == 0) {
#pragma unroll
                for (int i = 0; i < 8; i += 2) {
                    int pr = wvid * 8 + i;
                    int bb = pr >> 2, pp = pr & 3;   // pp even
                    astore64(sbuf + (size_t)(b0 + bb) * 64 + ug * 2 + (pp >> 1),
                             fpack2(s8[i], s8[i + 1]));
                }
            }
        }
        __asm__ volatile("s_waitcnt vmcnt(0)" ::: "memory");
        __syncthreads();
        if (tid == 0) astore64(&dnB[ug], TOFF + (unsigned long long)(3 * t + 2));

        // ---- phase C: softmax over p (redundant per block) + r update
        {
            const unsigned long long expt = TOFF + (unsigned long long)(3 * t + 2);
            if (tid < 32) {
                unsigned long long v = aload64(dnB + tid);
                int guard = 0;
                while (!__all(v >= expt)) {
                    if (++guard > SPIN_CAP) break;
                    __builtin_amdgcn_s_sleep(1);
                    if (v < expt) v = aload64(dnB + tid);
                }
            }
            __syncthreads();
            __asm__ volatile("" ::: "memory");
            const unsigned long long* src = sbuf + (size_t)b0 * 64;
#pragma unroll
            for (int i = 0; i < 2; i++) {
                int idx = tid + i * 256;
                int bb = idx >> 6, j = idx & 63;
                float2 f = funpack2(aload64(src + bb * 64 + j));
                *(float2*)&scst[bb][2 * j] = f;
            }
        }
        __syncthreads();
        {
            const int bb = tid >> 5, j = tid & 31;
            float4 v = *(float4*)&scst[bb][j * 4];
            float mx = fmaxf(fmaxf(v.x, v.y), fmaxf(v.z, v.w));
#pragma unroll
            for (int o = 1; o < 32; o <<= 1) mx = fmaxf(mx, __shfl_xor(mx, o));
            float ex = __expf(v.x - mx), ey = __expf(v.y - mx);
            float ez = __expf(v.z - mx), ew = __expf(v.w - mx);
            float ssum = (ex + ey) + (ez + ew);
#pragma unroll
            for (int o = 1; o < 32; o <<= 1) ssum += __shfl_xor(ssum, o);
            float inv = 1.0f / ssum;
            float4 sc4 = make_float4(ex * inv, ey * inv, ez * inv, ew * inv);
            *(float4*)&scst[bb][j * 4] = sc4;
        }
        __syncthreads();
        if (tid < 128) {
            float acc = tts[uuc][bbc];
            const float* opb = ops + bbc * OSTR + uuc;
#pragma unroll 8
            for (int p = 0; p < PLEN; p++)
                acc += scst[bbc][p] * opb[p * 16];
            float pr = __shfl_xor(acc, 1);
            if ((uuc & 1) == 0)
                astore64(rwr + (size_t)(b0 + bbc) * 256 + (u0 + uuc) / 2, fpack2(acc, pr));
        }
        __asm__ volatile("s_waitcnt vmcnt(0)" ::: "memory");
        __syncthreads();
        if (tid == 0) astore64(&dnC[ug], TOFF + (unsigned long long)(3 * t + 3));
    }
}

// ---------------------------------------------------------------------------
// final: rep = tanh(r.fc1^T + b1 + hn.fc2^T + b2); out = rep.fc3^T + b3
__global__ __launch_bounds__(256) void final_kernel(
    const unsigned long long* __restrict__ r2, const float* __restrict__ outh,
    const float* __restrict__ fc1w, const float* __restrict__ fc1b,
    const float* __restrict__ fc2w, const float* __restrict__ fc2b,
    const float* __restrict__ fc3w, const float* __restrict__ fc3b,
    float* __restrict__ out)
{
    int b = blockIdx.x, tid = threadIdx.x;
    __shared__ float rs[HDIM], hs[HDIM], rep[HDIM], red[256];
    {
        float2 f = funpack2(r2[(size_t)b * 256 + tid]);
        rs[2 * tid] = f.x; rs[2 * tid + 1] = f.y;
    }
    for (int i = tid; i < 128; i += 256)
        ((float4*)hs)[i] = ((const float4*)(outh + ((size_t)(b * HLEN + HLEN - 1)) * HDIM))[i];
    __syncthreads();
    for (int u = tid; u < HDIM; u += 256) {
        const float4* w1 = (const float4*)(fc1w + (size_t)u * HDIM);
        const float4* w2 = (const float4*)(fc2w + (size_t)u * HDIM);
        float a = 0.f, bacc = 0.f;
        for (int k = 0; k < 128; k++) {
            float4 rv = ((float4*)rs)[k], hv = ((float4*)hs)[k];
            float4 x = w1[k]; a    += rv.x * x.x + rv.y * x.y + rv.z * x.z + rv.w * x.w;
            float4 y = w2[k]; bacc += hv.x * y.x + hv.y * y.y + hv.z * y.z + hv.w * y.w;
        }
        rep[u] = tanhfast(a + fc1b[u] + bacc + fc2b[u]);
    }
    __syncthreads();
    for (int cix = 0; cix < NCLS; cix++) {
        red[tid] = rep[tid] * fc3w[(size_t)cix * HDIM + tid]
                 + rep[tid + 256] * fc3w[(size_t)cix * HDIM + tid + 256];
        __syncthreads();
        for (int off = 128; off; off >>= 1) {
            if (tid < off) red[tid] += red[tid + off];
            __syncthreads();
        }
        if (tid == 0) out[b * NCLS + cix] = red[0] + fc3b[cix];
        __syncthreads();
    }
}

// ---------------------------------------------------------------------------
extern "C" void kernel_launch(void* const* d_in, const int* in_sizes, int n_in,
                              void* d_out, int out_size, void* d_ws, size_t ws_size,
                              hipStream_t stream)
{
    const int*   premise = (const int*)d_in[0];
    const int*   hyp     = (const int*)d_in[1];
    const float* emb     = (const float*)d_in[2];
    const float* Wih1    = (const float*)d_in[3];
    const float* Whh1    = (const float*)d_in[4];
    const float* bih1    = (const float*)d_in[5];
    const float* bhh1    = (const float*)d_in[6];
    const float* Wih2    = (const float*)d_in[7];
    const float* Whh2    = (const float*)d_in[8];
    const float* bih2    = (const float*)d_in[9];
    const float* bhh2    = (const float*)d_in[10];
    const float* Wy      = (const float*)d_in[11];
    const float* Wh      = (const float*)d_in[12];
    const float* Wr      = (const float*)d_in[13];
    const float* Wt      = (const float*)d_in[14];
    const float* wv      = (const float*)d_in[15];
    const float* fc1w    = (const float*)d_in[16];
    const float* fc1b    = (const float*)d_in[17];
    const float* fc2w    = (const float*)d_in[18];
    const float* fc2b    = (const float*)d_in[19];
    const float* fc3w    = (const float*)d_in[20];
    const float* fc3b    = (const float*)d_in[21];
    float* out = (float*)d_out;

    float* ws = (float*)d_ws;
    size_t off = 0;
    float* xp    = ws + off; off += (size_t)BSZ * PLEN * G4;
    float* xh    = ws + off; off += (size_t)BSZ * HLEN * G4;
    float* outp  = ws + off; off += (size_t)BSZ * PLEN * HDIM;
    float* outhp = ws + off; off += (size_t)BSZ * HLEN * HDIM;
    float* a1b   = ws + off; off += (size_t)BSZ * HDIM * PLEN;   // [b][p][h]
    // packed-float2 u64 exchange buffers + done words
    unsigned long long* tbase = (unsigned long long*)(ws + off);
    unsigned long long* hAb   = tbase;                    // 16384 each (64*256)
    unsigned long long* hBb   = tbase + 16384;
    unsigned long long* hCb   = tbase + 2 * 16384;        // also att rA
    unsigned long long* hDb   = tbase + 3 * 16384;        // also att rB
    unsigned long long* a2b   = tbase + 4 * 16384;
    unsigned long long* sbb   = tbase + 5 * 16384;        // 4096 (64*64)
    unsigned long long* dnH   = tbase + 5 * 16384 + 4096; // 256 each
    unsigned long long* dnA   = dnH + 256;
    unsigned long long* dnB   = dnA + 256;
    unsigned long long* dnC   = dnB + 256;
    off += (size_t)(5 * 16384 + 4096 + 1024) * 2;         // in floats
    if (ws_size < off * sizeof(float)) return;

    // zero ONLY the done words (1024 u64 = 4 * 256)
    ws_zero<<<dim3(4), dim3(256), 0, stream>>>(dnH);

    // input projections (biases folded in): 32x64 tiles
    proj_kernel<<<dim3(BSZ * PLEN / 32, G4 / 64), dim3(256), 0, stream>>>(
        premise, emb, Wih1, bih1, bhh1, xp);
    proj_kernel<<<dim3(BSZ * HLEN / 32, G4 / 64), dim3(256), 0, stream>>>(
        hyp, emb, Wih2, bih2, bhh2, xh);

    // both LSTMs, persistent, done-word sync (layer2 h via hC/hD)
    lstm_coop<<<dim3(256), dim3(256), 0, stream>>>(
        xp, xh, Whh1, Whh2, outp, outhp, hAb, hBb, hCb, hDb, dnH);

    // a1t = einsum('hj,bpj->bph', Wy, outp)
    a1_kernel<<<dim3(BSZ, PLEN / 32, HDIM / 64), dim3(256), 0, stream>>>(Wy, outp, a1b);

    // attention recurrence, persistent, done-word sync
    att_coop<<<dim3(256), dim3(256), 0, stream>>>(
        outhp, a1b, outp, Wh, Wr, Wt, wv, a2b, sbb, hCb, hDb, dnA, dnB, dnC);

    // final classifier: r after step 63 lives in rB (63 & 1 == 1)
    final_kernel<<<dim3(BSZ), dim3(256), 0, stream>>>(
        hDb, outhp, fc1w, fc1b, fc2w, fc2b, fc3w, fc3b, out);
}